// Round 5
// baseline (2575.323 us; speedup 1.0000x reference)
//
#include <hip/hip_runtime.h>
#include <math.h>

// PerceiverResampler on MI355X.
// xhat = rownorm(x + frame_emb + media_emb) once (bf16); per-layer LN affine folded
// into Wkv. GEMMs bf16 MFMA 16x16x32, fp32 accum, weights pre-transposed [N][K].
// kv-GEMM: 256x256 tile, BK=64, 8 waves, 8-phase schedule with ONE barrier/phase,
// fragment read-ahead (frags for phase p read during p-1), A 3-deep / B 2-deep LDS
// (160 KB), counted vmcnt(8) gates, slot^(row&7) conflict-free swizzle, XCD swizzle.

#define DIM   1024
#define DEPTH 6
#define HEADS 8
#define NLAT  64
#define INNER 512
#define FFD   4096
#define XROWS 65536
#define LROWS 1024
#define NBT   16
#define QKVN  1536

typedef __attribute__((ext_vector_type(8))) short bf16x8;
typedef __attribute__((ext_vector_type(4))) float f32x4;

#define WAITV(n) asm volatile("s_waitcnt vmcnt(" #n ")" ::: "memory")

__device__ __forceinline__ short f2bf(float f) {
  union { float f; unsigned u; } v; v.f = f;
  unsigned r = v.u + 0x7fffu + ((v.u >> 16) & 1u);
  return (short)(r >> 16);
}

__device__ __forceinline__ void gload16(const void* g, void* l) {
  __builtin_amdgcn_global_load_lds(
      (const __attribute__((address_space(1))) unsigned int*)g,
      (__attribute__((address_space(3))) unsigned int*)l, 16, 0, 0);
}

__device__ __forceinline__ f32x4 zero_f4() { f32x4 z; z[0]=0.f; z[1]=0.f; z[2]=0.f; z[3]=0.f; return z; }
__device__ __forceinline__ bf16x8 zero_b8() { bf16x8 z;
#pragma unroll
  for (int e=0;e<8;e++) z[e]=0; return z; }

// ---------------- preprocess ----------------
__global__ __launch_bounds__(256)
void prep_kernel(const float* __restrict__ x, const float* __restrict__ fe,
                 const float* __restrict__ me, short* __restrict__ xhat)
{
  int lane = threadIdx.x & 63;
  int r = blockIdx.x*4 + (threadIdx.x >> 6);
  int f = (r >> 8) & 15, tt = (r >> 12) & 7;
  const float4* xp = (const float4*)(x + (size_t)r*DIM);
  const float4* fp = (const float4*)(fe + (size_t)f*DIM);
  const float4* mp = (const float4*)(me + (size_t)tt*DIM);
  float y[16];
  float s = 0.f, sq = 0.f;
#pragma unroll
  for (int k = 0; k < 4; k++) {
    float4 xv = xp[k*64 + lane], fv = fp[k*64 + lane], mv = mp[k*64 + lane];
    float a0 = xv.x+fv.x+mv.x, a1 = xv.y+fv.y+mv.y, a2 = xv.z+fv.z+mv.z, a3 = xv.w+fv.w+mv.w;
    y[k*4+0]=a0; y[k*4+1]=a1; y[k*4+2]=a2; y[k*4+3]=a3;
    s += a0+a1+a2+a3; sq += a0*a0+a1*a1+a2*a2+a3*a3;
  }
#pragma unroll
  for (int off = 32; off >= 1; off >>= 1) {
    s  += __shfl_xor(s,  off, 64);
    sq += __shfl_xor(sq, off, 64);
  }
  float mean = s * (1.0f/DIM);
  float var  = sq * (1.0f/DIM) - mean*mean;
  float rs = rsqrtf(var + 1e-5f);
  short4* op = (short4*)(xhat + (size_t)r*DIM);
#pragma unroll
  for (int k = 0; k < 4; k++) {
    short4 o;
    o.x = f2bf((y[k*4+0]-mean)*rs); o.y = f2bf((y[k*4+1]-mean)*rs);
    o.z = f2bf((y[k*4+2]-mean)*rs); o.w = f2bf((y[k*4+3]-mean)*rs);
    op[k*64 + lane] = o;
  }
}

// ---------------- LN ----------------
__device__ __forceinline__ void reduce2(float& s, float& sq, float* sh) {
#pragma unroll
  for (int off = 32; off >= 1; off >>= 1) {
    s  += __shfl_xor(s,  off, 64);
    sq += __shfl_xor(sq, off, 64);
  }
  int t = threadIdx.x;
  if ((t & 63) == 0) { sh[(t >> 6)*2] = s; sh[(t >> 6)*2 + 1] = sq; }
  __syncthreads();
  s  = sh[0] + sh[2] + sh[4] + sh[6];
  sq = sh[1] + sh[3] + sh[5] + sh[7];
}

template<bool OBF>
__global__ __launch_bounds__(256)
void ln_kernel(const float* __restrict__ in, const float* __restrict__ w,
               const float* __restrict__ b, void* __restrict__ outp)
{
  __shared__ float sh[8];
  int r = blockIdx.x, t = threadIdx.x;
  float4 xv = ((const float4*)(in + (size_t)r*DIM))[t];
  float s = xv.x+xv.y+xv.z+xv.w;
  float sq = xv.x*xv.x+xv.y*xv.y+xv.z*xv.z+xv.w*xv.w;
  reduce2(s, sq, sh);
  float mean = s*(1.0f/DIM), var = sq*(1.0f/DIM) - mean*mean;
  float rs = rsqrtf(var + 1e-5f);
  float4 wv = ((const float4*)w)[t], bv = ((const float4*)b)[t];
  float o0 = (xv.x-mean)*rs*wv.x + bv.x;
  float o1 = (xv.y-mean)*rs*wv.y + bv.y;
  float o2 = (xv.z-mean)*rs*wv.z + bv.z;
  float o3 = (xv.w-mean)*rs*wv.w + bv.w;
  if (OBF) {
    short4 o; o.x=f2bf(o0); o.y=f2bf(o1); o.z=f2bf(o2); o.w=f2bf(o3);
    ((short4*)((short*)outp + (size_t)r*DIM))[t] = o;
  } else {
    float4 o; o.x=o0; o.y=o1; o.z=o2; o.w=o3;
    ((float4*)((float*)outp + (size_t)r*DIM))[t] = o;
  }
}

// ---------------- lat init ----------------
__global__ __launch_bounds__(256)
void latinit_kernel(const float* __restrict__ latents, float* __restrict__ lat)
{
  int idx = blockIdx.x * 256 + threadIdx.x;
  int e = idx << 2;
  int row = e >> 10;
  int i = row & 63;
  int col = e & 1023;
  *(float4*)(lat + e) = *(const float4*)(latents + (i << 10) + col);
}

// ---------------- kvb: split-K partials + reduce ----------------
__global__ __launch_bounds__(256)
void kvbp_kernel(const float* __restrict__ lnm_b, const float* __restrict__ Wkv,
                 float* __restrict__ kvb_part)
{
  int z = blockIdx.x, i = blockIdx.y, t = threadIdx.x;
  const float* W = Wkv + (size_t)i*DIM*DIM;
  const float* bv = lnm_b + (size_t)i*DIM;
  float acc0=0,acc1=0,acc2=0,acc3=0;
  for (int k = z*64; k < z*64+64; k++) {
    float b = bv[k];
    const float* Wr = W + (size_t)k*DIM;
    acc0 += b * Wr[t];       acc1 += b * Wr[t+256];
    acc2 += b * Wr[t+512];   acc3 += b * Wr[t+768];
  }
  float* o = kvb_part + (size_t)(i*16 + z)*DIM;
  o[t] = acc0; o[t+256] = acc1; o[t+512] = acc2; o[t+768] = acc3;
}

__global__ __launch_bounds__(256)
void kvbred_kernel(const float* __restrict__ kvb_part, float* __restrict__ kvb)
{
  int i = blockIdx.x, t = threadIdx.x;
#pragma unroll
  for (int j = 0; j < 4; j++) {
    int col = t + j*256;
    float s = 0.f;
#pragma unroll
    for (int z = 0; z < 16; z++) s += kvb_part[(size_t)(i*16 + z)*DIM + col];
    kvb[i*DIM + col] = s;
  }
}

// ---------------- batched transpose-cast ----------------
__global__ __launch_bounds__(256)
void tcast_all_kernel(const float* __restrict__ Wkv, const float* __restrict__ Wq,
                      const float* __restrict__ Wo, const float* __restrict__ W1,
                      const float* __restrict__ W2, const float* __restrict__ lnmw,
                      short* __restrict__ Wkv_f, short* __restrict__ qkvW,
                      short* __restrict__ Wo_h, short* __restrict__ W1_h,
                      short* __restrict__ W2_h)
{
  int b = blockIdx.x;
  const float* src; short* dst; const float* fold = nullptr; float scale = 1.0f;
  int K, N, bx, ntx;
  if (b < 256)      { src=Wkv; dst=Wkv_f; fold=lnmw; K=1024; N=1024; bx=b;      ntx=16; }
  else if (b < 384) { src=Wq;  dst=qkvW;  scale=0.125f; K=1024; N=512; bx=b-256; ntx=8; }
  else if (b < 640) { src=Wkv; dst=qkvW+512*1024; K=1024; N=1024; bx=b-384; ntx=16; }
  else if (b < 768) { src=Wo;  dst=Wo_h;  K=512;  N=1024; bx=b-640; ntx=16; }
  else if (b < 1792){ src=W1;  dst=W1_h;  K=1024; N=4096; bx=b-768; ntx=64; }
  else              { src=W2;  dst=W2_h;  K=4096; N=1024; bx=b-1792; ntx=16; }
  int n0 = (bx % ntx)*64, k0 = (bx / ntx)*64;
  __shared__ float tile[64][65];
  int t = threadIdx.x;
#pragma unroll
  for (int i = 0; i < 16; i++) {
    int rr = (t >> 6) + i*4, cc = t & 63;
    float v = src[(size_t)(k0+rr)*N + n0 + cc] * scale;
    if (fold) v *= fold[k0 + rr];
    tile[rr][cc] = v;
  }
  __syncthreads();
#pragma unroll
  for (int i = 0; i < 16; i++) {
    int nn = (t >> 6) + i*4, kk = t & 63;
    dst[(size_t)(n0+nn)*K + k0 + kk] = f2bf(tile[kk][nn]);
  }
}

// ---------------- 256x256 read-ahead pipelined GEMM (kv projection) ----------------
// C[M][N](bf16) = A[M][K] @ Bt[N][K] + bias. K % 128 == 0, K >= 512.
// LDS: A 3 bufs (t%3) + B 2 bufs (t%2), 32 KB each = 160 KB total.
// Per phase: {barrier; read-ahead next-phase frags; stage; MFMA on prev-read frags}.
// Gates: vmcnt(8) end-p2/p6 steady; tail vmcnt(0).
__global__ __launch_bounds__(512, 2)
void gemm256p_kernel(const short* __restrict__ A, const short* __restrict__ Bt,
                     short* __restrict__ C, const float* __restrict__ bias,
                     int M, int N, int K)
{
  __shared__ __align__(16) short lds[81920];   // 160 KiB
  char* ldsc = (char*)lds;
  const int t = threadIdx.x, lane = t & 63, wid = t >> 6;
  const int wm = wid >> 2, wn = wid & 3;

  const int nwg = gridDim.x * gridDim.y;
  const int id = blockIdx.y * gridDim.x + blockIdx.x;
  const int work = (id & 7) * (nwg >> 3) + (id >> 3);
  const int bn = work % gridDim.x, bm = work / gridDim.x;
  const int m0 = bm * 256, n0 = bn * 256;

  f32x4 acc[8][4];
#pragma unroll
  for (int m=0;m<8;m++)
#pragma unroll
    for (int n=0;n<4;n++) acc[m][n] = zero_f4();

  // half-tile stage: 128 rows x 64 cols, 2 gloads/thread, pre-swizzled source.
  auto stage_A = [&](int tile, int abuf, int half) {
#pragma unroll
    for (int i = 0; i < 2; i++) {
      int c = i*512 + t;
      int rh = c >> 3, sl = c & 7;
      int ss = sl ^ (rh & 7);
      gload16(A + (size_t)(m0 + half*128 + rh)*K + tile*64 + ss*8,
              ldsc + abuf*32768 + half*16384 + (i*512 + (wid<<6))*16);
    }
  };
  auto stage_B = [&](int tile, int bbuf, int half) {
#pragma unroll
    for (int i = 0; i < 2; i++) {
      int c = i*512 + t;
      int rh = c >> 3, sl = c & 7;
      int ss = sl ^ (rh & 7);
      gload16(Bt + (size_t)(n0 + half*128 + rh)*K + tile*64 + ss*8,
              ldsc + 98304 + bbuf*32768 + half*16384 + (i*512 + (wid<<6))*16);
    }
  };

  bf16x8 af0[2][2], af1[2][2];      // A frag ping-pong (2 m-frags x 2 k-slots)
  bf16x8 bg0[4][2], bg1[4][2];      // B frag groups (4 n-frags x 2 k-slots)

#define LD_A(DST, ABUF, Q)                                                  \
  { _Pragma("unroll") for (int i_=0;i_<2;i_++)                              \
      _Pragma("unroll") for (int k_=0;k_<2;k_++) {                          \
        int row_ = wm*128 + (2*(Q)+i_)*16 + (lane & 15);                    \
        int sl_ = (k_*4 + (lane >> 4)) ^ (row_ & 7);                        \
        DST[i_][k_] = *(const bf16x8*)(ldsc + (ABUF)*32768 + row_*128 + sl_*16); } }

#define LD_B(DST, BBUF)                                                     \
  { _Pragma("unroll") for (int n_=0;n_<4;n_++)                              \
      _Pragma("unroll") for (int k_=0;k_<2;k_++) {                          \
        int row_ = wn*64 + n_*16 + (lane & 15);                             \
        int sl_ = (k_*4 + (lane >> 4)) ^ (row_ & 7);                        \
        DST[n_][k_] = *(const bf16x8*)(ldsc + 98304 + (BBUF)*32768 + row_*128 + sl_*16); } }

#define MM(AF, BG, Q)                                                       \
  { __builtin_amdgcn_s_setprio(1);                                          \
    _Pragma("unroll") for (int k_=0;k_<2;k_++)                              \
      _Pragma("unroll") for (int i_=0;i_<2;i_++)                            \
        _Pragma("unroll") for (int n_=0;n_<4;n_++)                          \
          acc[2*(Q)+i_][n_] = __builtin_amdgcn_mfma_f32_16x16x32_bf16(      \
              AF[i_][k_], BG[n_][k_], acc[2*(Q)+i_][n_], 0, 0, 0);          \
    __builtin_amdgcn_s_setprio(0); }

#define BARP { __builtin_amdgcn_s_barrier(); __builtin_amdgcn_sched_barrier(0); }

  const int NU = K >> 7;   // iterations of 2 K-tiles

  // prologue: A(0),B(0),A(1),B(1),A(2) = 20 loads
  stage_A(0, 0, 0); stage_A(0, 0, 1);
  stage_B(0, 0, 0); stage_B(0, 0, 1);
  stage_A(1, 1, 0); stage_A(1, 1, 1);
  stage_B(1, 1, 0); stage_B(1, 1, 1);
  stage_A(2, 2, 0); stage_A(2, 2, 1);
  WAITV(12);                          // A(0),B(0) resident
  BARP;
  LD_B(bg0, 0);
  LD_A(af0, 0, 0);

  int ab0 = 0, ab1 = 1, ab2 = 2;
#pragma unroll 1
  for (int u = 0; u < NU; ++u) {
    const int t0 = 2*u;
    const bool more = (u + 1 < NU);
    // p0
    BARP;
    LD_A(af1, ab0, 1);
    if (u > 0 && more) stage_A(t0+2, ab2, 1);
    MM(af0, bg0, 0);
    // p1
    BARP;
    LD_A(af0, ab0, 2);
    if (more) stage_B(t0+2, 0, 0);
    MM(af1, bg0, 1);
    // p2
    BARP;
    LD_A(af1, ab0, 3);
    if (more) stage_B(t0+2, 0, 1);
    MM(af0, bg0, 2);
    if (more) { WAITV(8); } else { WAITV(0); }
    // p3
    BARP;
    LD_A(af0, ab1, 0);
    LD_B(bg1, 1);
    if (more) stage_A(t0+3, ab0, 0);
    MM(af1, bg0, 3);
    // p4
    BARP;
    LD_A(af1, ab1, 1);
    if (more) stage_A(t0+3, ab0, 1);
    MM(af0, bg1, 0);
    // p5
    BARP;
    LD_A(af0, ab1, 2);
    if (more) stage_B(t0+3, 1, 0);
    MM(af1, bg1, 1);
    // p6
    BARP;
    LD_A(af1, ab1, 3);
    if (more) stage_B(t0+3, 1, 1);
    MM(af0, bg1, 2);
    if (more) { WAITV(8); }
    // p7
    BARP;
    if (more) {
      LD_A(af0, ab2, 0);
      LD_B(bg0, 0);
    }
    if (u + 2 < NU) stage_A(t0+4, ab1, 0);
    MM(af1, bg1, 3);
    // rotate A buffers: next iter's (t0+2)%3 = ab2
    int tmp = ab2; ab2 = ab1; ab1 = ab0; ab0 = tmp;
  }
#undef LD_A
#undef LD_B
#undef MM
#undef BARP

  const int g = lane >> 4;
#pragma unroll
  for (int m=0;m<8;m++) {
#pragma unroll
    for (int n=0;n<4;n++) {
#pragma unroll
      for (int r=0;r<4;r++) {
        int mm = m0 + wm*128 + m*16 + g*4 + r;
        int nn = n0 + wn*64 + n*16 + (lane & 15);
        float v = acc[m][n][r] + bias[nn];
        C[(size_t)mm*N + nn] = f2bf(v);
      }
    }
  }
}

// ---------------- 128x128 GEMM for small shapes ----------------
// EPI: 0 bf16 store, 1 gelu+bf16, 2 f32 +=, 4 f32 partial store (split-K z)
template<int EPI, bool HAS_BIAS>
__global__ __launch_bounds__(256, 2)
void gemm_kernel(const short* __restrict__ A, const short* __restrict__ Bt,
                 void* __restrict__ Cout, const float* __restrict__ bias,
                 int M, int N, int K, int ldk)
{
  __shared__ __align__(16) short As[128*64];
  __shared__ __align__(16) short Bs[128*64];
  const int t = threadIdx.x;
  const int lane = t & 63, w = t >> 6;
  const int m0 = blockIdx.x * 128, n0 = blockIdx.y * 128;
  const int wr = (w >> 1) * 64, wc = (w & 1) * 64;
  const short* Ap = A + (size_t)blockIdx.z * K;
  const short* Btp = Bt + (size_t)blockIdx.z * K;

  f32x4 acc[4][4];
#pragma unroll
  for (int i=0;i<4;i++)
#pragma unroll
    for (int j=0;j<4;j++) acc[i][j] = zero_f4();

  for (int kt = 0; kt < K; kt += 64) {
#pragma unroll
    for (int i = 0; i < 4; i++) {
      int chunk = i*256 + t;
      int row = chunk >> 3, slot = chunk & 7;
      int ss = slot ^ (row & 7);
      gload16(Ap + (size_t)(m0 + row)*ldk + kt + ss*8,
              (char*)As + (i*256 + (w<<6))*16);
    }
#pragma unroll
    for (int i = 0; i < 4; i++) {
      int chunk = i*256 + t;
      int row = chunk >> 3, slot = chunk & 7;
      int ss = slot ^ (row & 7);
      gload16(Btp + (size_t)(n0 + row)*ldk + kt + ss*8,
              (char*)Bs + (i*256 + (w<<6))*16);
    }
    __syncthreads();

#pragma unroll
    for (int ks = 0; ks < 2; ks++) {
      bf16x8 af[4], bfr[4];
#pragma unroll
      for (int i=0;i<4;i++) {
        int row = wr + i*16 + (lane & 15);
        int slot = (ks*4 + (lane >> 4)) ^ (row & 7);
        af[i] = *(const bf16x8*)((const char*)As + row*128 + slot*16);
        int nrow = wc + i*16 + (lane & 15);
        int nslot = (ks*4 + (lane >> 4)) ^ (nrow & 7);
        bfr[i] = *(const bf16x8*)((const char*)Bs + nrow*128 + nslot*16);
      }
#pragma unroll
      for (int i=0;i<4;i++)
#pragma unroll
        for (int j=0;j<4;j++)
          acc[i][j] = __builtin_amdgcn_mfma_f32_16x16x32_bf16(af[i], bfr[j], acc[i][j], 0, 0, 0);
    }
    __syncthreads();
  }

  const int g = lane >> 4;
#pragma unroll
  for (int i=0;i<4;i++) {
#pragma unroll
    for (int j=0;j<4;j++) {
#pragma unroll
      for (int r=0;r<4;r++) {
        int m = m0 + wr + i*16 + g*4 + r;
        int n = n0 + wc + j*16 + (lane & 15);
        float v = acc[i][j][r];
        if (EPI == 0) {
          if (HAS_BIAS) v += bias[n];
          ((short*)Cout)[(size_t)m*N + n] = f2bf(v);
        } else if (EPI == 1) {
          if (HAS_BIAS) v += bias[n];
          float gl = 0.5f * v * (1.0f + erff(v * 0.70710678f));
          ((short*)Cout)[(size_t)m*N + n] = f2bf(gl);
        } else if (EPI == 2) {
          if (HAS_BIAS) v += bias[n];
          float* o = (float*)Cout + (size_t)m*N + n;
          *o += v;
        } else {
          ((float*)Cout)[(size_t)blockIdx.z*M*N + (size_t)m*N + n] = v;
        }
      }
    }
  }
}

// ---------------- W2 split-K reduce ----------------
__global__ __launch_bounds__(256)
void w2red_kernel(const float* __restrict__ part, const float* __restrict__ b2,
                  float* __restrict__ lat)
{
  int idx = blockIdx.x * 256 + threadIdx.x;
  float4 a = ((float4*)lat)[idx];
  float4 bb = ((const float4*)b2)[idx & 255];
  a.x += bb.x; a.y += bb.y; a.z += bb.z; a.w += bb.w;
#pragma unroll
  for (int z = 0; z < 4; z++) {
    float4 p = ((const float4*)(part + (size_t)z*LROWS*DIM))[idx];
    a.x += p.x; a.y += p.y; a.z += p.z; a.w += p.w;
  }
  ((float4*)lat)[idx] = a;
}

// ---------------- attention pass 1 ----------------
__global__ __launch_bounds__(256, 2)
void attn_part_kernel(const short* __restrict__ qkvlat, const short* __restrict__ kvbuf,
                      float* __restrict__ part_O, float* __restrict__ part_m,
                      float* __restrict__ part_l)
{
  __shared__ __align__(16) short q_sh[64*64];
  __shared__ __align__(16) short K_sh[128*64];
  __shared__ __align__(16) short VT_sh[64*128];
  __shared__ __align__(16) short P_sh[64*132];

  const int t = threadIdx.x, lane = t & 63, w = t >> 6;
  const int bid = blockIdx.x;
  const int s = bid & 7, bh = bid >> 3;
  const int h = bh & 7, bt = bh >> 3;

  {
    const short* qsrc = qkvlat + (size_t)(bt*64)*QKVN + h*64;
#pragma unroll
    for (int i = 0; i < 2; i++) {
      int chunk = i*256 + t;
      int row = chunk >> 3, slot = chunk & 7;
      gload16(qsrc + (size_t)row*QKVN + ((slot ^ (row & 7))*8),
              (char*)q_sh + (i*256 + (w<<6))*16);
    }
  }

  float m_run[4], l_run[4];
#pragma unroll
  for (int r=0;r<4;r++){ m_run[r] = -1e30f; l_run[r] = 0.f; }
  f32x4 oacc[4];
#pragma unroll
  for (int j=0;j<4;j++) oacc[j] = zero_f4();

  const int nch = (s == 7) ? 5 : 4;
  for (int c5 = 0; c5 < nch; c5++) {
    __syncthreads();
    const bool isLat = (c5 == 4);
    const int jv = isLat ? 4 : 8;
    const short* kbase; int kstride, valid;
    if (!isLat) {
      kbase = kvbuf + ((size_t)bt*4096 + (s*4 + c5)*128)*DIM + h*64;
      kstride = DIM; valid = 128;
    } else {
      kbase = qkvlat + (size_t)(bt*64)*QKVN + 512 + h*64;
      kstride = QKVN; valid = 64;
    }
    const short* vbase = kbase + 512;

#pragma unroll
    for (int i = 0; i < 4; i++) {
      int chunk = i*256 + t;
      int row = chunk >> 3, slot = chunk & 7;
      gload16(kbase + (size_t)row*kstride + ((slot ^ (row & 7))*8),
              (char*)K_sh + (i*256 + (w<<6))*16);
    }
#pragma unroll
    for (int i = 0; i < 4; i++) {
      int c = i*256 + t;
      int row = c >> 3, slot = c & 7;
      bf16x8 v = (row < valid) ? *(const bf16x8*)(vbase + (size_t)row*kstride + slot*8) : zero_b8();
      int kslot = row >> 3;
#pragma unroll
      for (int e=0;e<8;e++) {
        int dh = slot*8 + e;
        VT_sh[dh*128 + ((kslot ^ (dh & 7))*8) + (row & 7)] = v[e];
      }
    }
    __syncthreads();

    f32x4 sacc[8];
#pragma unroll
    for (int j=0;j<8;j++) sacc[j] = zero_f4();
#pragma unroll
    for (int ks=0; ks<2; ks++) {
      int arow = w*16 + (lane & 15);
      int aslot = (ks*4 + (lane >> 4)) ^ (arow & 7);
      bf16x8 af = *(const bf16x8*)((const char*)q_sh + arow*128 + aslot*16);
#pragma unroll
      for (int j=0;j<8;j++) {
        int brow = j*16 + (lane & 15);
        int bslot = (ks*4 + (lane >> 4)) ^ (brow & 7);
        bf16x8 bv = *(const bf16x8*)((const char*)K_sh + brow*128 + bslot*16);
        sacc[j] = __builtin_amdgcn_mfma_f32_16x16x32_bf16(af, bv, sacc[j], 0, 0, 0);
      }
    }

    float mx[4];
#pragma unroll
    for (int r=0;r<4;r++) mx[r] = -1e30f;
#pragma unroll
    for (int j=0;j<8;j++) {
      if (j < jv) {
#pragma unroll
        for (int r=0;r<4;r++) mx[r] = fmaxf(mx[r], sacc[j][r]);
      }
    }
#pragma unroll
    for (int m2=1; m2<16; m2<<=1) {
#pragma unroll
      for (int r=0;r<4;r++) mx[r] = fmaxf(mx[r], __shfl_xor(mx[r], m2, 64));
    }
    float alpha[4], rowsum[4];
#pragma unroll
    for (int r=0;r<4;r++) {
      float nm = fmaxf(m_run[r], mx[r]);
      alpha[r] = __expf(m_run[r] - nm);
      m_run[r] = nm;
      rowsum[r] = 0.f;
    }
#pragma unroll
    for (int j=0;j<8;j++) {
#pragma unroll
      for (int r=0;r<4;r++) {
        float p = 0.f;
        if (j < jv) { p = __expf(sacc[j][r] - m_run[r]); rowsum[r] += p; }
        P_sh[(w*16 + (lane>>4)*4 + r)*132 + j*16 + (lane & 15)] = f2bf(p);
      }
    }
#pragma unroll
    for (int m2=1; m2<16; m2<<=1) {
#pragma unroll
      for (int r=0;r<4;r++) rowsum[r] += __shfl_xor(rowsum[r], m2, 64);
    }
#pragma unroll
    for (int r=0;r<4;r++) l_run[r] = l_run[r]*alpha[r] + rowsum[r];
#pragma unroll
    for (int j=0;j<4;j++) {
#pragma unroll
      for (int r=0;r<4;r++) oacc[j][r] *= alpha[r];
    }
    __syncthreads();

#pragma unroll
    for (int ks=0; ks<4; ks++) {
      int prow = w*16 + (lane & 15);
      bf16x8 af = *(const bf16x8*)((const char*)P_sh + prow*264 + ks*64 + (lane >> 4)*16);
#pragma unroll
      for (int j=0;j<4;j++) {
        int dh = j*16 + (lane & 15);
        int kslot = (ks*4 + (lane >> 4)) ^ (dh & 7);
        bf16x8 bv = *(const bf16x8*)((const char*)VT_sh + dh*256 + kslot*16);
        oacc[j] = __builtin_amdgcn_mfma_f32_16x16x32_bf16(af, bv, oacc[j], 0, 0, 0);
      }
    }
  }

  {
    float* Ob = part_O + (size_t)bid*4096;
    int rbase = w*16 + (lane>>4)*4;
#pragma unroll
    for (int j=0;j<4;j++) {
#pragma unroll
      for (int r=0;r<4;r++)
        Ob[(rbase + r)*64 + j*16 + (lane & 15)] = oacc[j][r];
    }
    if ((lane & 15) == 0) {
#pragma unroll
      for (int r=0;r<4;r++) {
        part_m[(size_t)bid*64 + rbase + r] = m_run[r];
        part_l[(size_t)bid*64 + rbase + r] = l_run[r];
      }
    }
  }
}

// ---------------- attention pass 2 ----------------
__global__ __launch_bounds__(256)
void attn_combine_kernel(const float* __restrict__ part_O, const float* __restrict__ part_m,
                         const float* __restrict__ part_l, short* __restrict__ obuf)
{
  int bh = blockIdx.x, t = threadIdx.x;
  int q = t >> 2, c0 = (t & 3) * 16;
  int bt = bh >> 3, h = bh & 7;
  float m8[8], w8[8];
  float mmax = -1e30f;
#pragma unroll
  for (int s=0;s<8;s++) { m8[s] = part_m[(size_t)(bh*8+s)*64 + q]; mmax = fmaxf(mmax, m8[s]); }
  float lt = 0.f;
#pragma unroll
  for (int s=0;s<8;s++) { w8[s] = __expf(m8[s] - mmax); lt += w8[s] * part_l[(size_t)(bh*8+s)*64 + q]; }
  float inv = 1.0f / lt;
  float4 acc[4];
#pragma unroll
  for (int u=0;u<4;u++) { acc[u].x=0.f; acc[u].y=0.f; acc[u].z=0.f; acc[u].w=0.f; }
#pragma unroll
  for (int s=0;s<8;s++) {
    const float4* Ob = (const float4*)(part_O + ((size_t)(bh*8+s)*64 + q)*64 + c0);
#pragma unroll
    for (int u=0;u<4;u++) {
      float4 v = Ob[u];
      acc[u].x += w8[s]*v.x; acc[u].y += w8[s]*v.y;
      acc[u].z += w8[s]*v.z; acc[u].w += w8[s]*v.w;
    }
  }
  short* ob = obuf + (size_t)(bt*64 + q)*INNER + h*64 + c0;
#pragma unroll
  for (int u=0;u<4;u++) {
    short4 o;
    o.x = f2bf(acc[u].x*inv); o.y = f2bf(acc[u].y*inv);
    o.z = f2bf(acc[u].z*inv); o.w = f2bf(acc[u].w*inv);
    ((short4*)ob)[u] = o;
  }
}

// ---------------- launch ----------------
extern "C" void kernel_launch(void* const* d_in, const int* in_sizes, int n_in,
                              void* d_out, int out_size, void* d_ws, size_t ws_size,
                              hipStream_t stream)
{
  (void)in_sizes; (void)n_in; (void)out_size; (void)ws_size;
  const float* x        = (const float*)d_in[0];
  const float* latents  = (const float*)d_in[1];
  const float* frame_e  = (const float*)d_in[2];
  const float* media_e  = (const float*)d_in[3];
  const float* lnm_w    = (const float*)d_in[4];
  const float* lnm_b    = (const float*)d_in[5];
  const float* lnl_w    = (const float*)d_in[6];
  const float* lnl_b    = (const float*)d_in[7];
  const float* Wq       = (const float*)d_in[8];
  const float* Wkv      = (const float*)d_in[9];
  const float* Wo       = (const float*)d_in[10];
  const float* ffln_w   = (const float*)d_in[11];
  const float* ffln_b   = (const float*)d_in[12];
  const float* W1       = (const float*)d_in[13];
  const float* b1       = (const float*)d_in[14];
  const float* W2       = (const float*)d_in[15];
  const float* b2       = (const float*)d_in[16];
  const float* fln_w    = (const float*)d_in[17];
  const float* fln_b    = (const float*)d_in[18];
  float* out = (float*)d_out;

  char* ws = (char*)d_ws;
  size_t off = 0;
  short* xhat   = (short*)(ws + off); off += (size_t)XROWS*DIM*2;
  short* kvbuf  = (short*)(ws + off); off += (size_t)XROWS*DIM*2;
  short* Wkv_f  = (short*)(ws + off); off += (size_t)DIM*DIM*2;
  short* qkvW   = (short*)(ws + off); off += (size_t)QKVN*DIM*2;
  short* Wo_h   = (short*)(ws + off); off += (size_t)INNER*DIM*2;
  short* W1_h   = (short*)(ws + off); off += (size_t)DIM*FFD*2;
  short* W2_h   = (short*)(ws + off); off += (size_t)FFD*DIM*2;
  float* kvb    = (float*)(ws + off); off += (size_t)DEPTH*DIM*4;
  float* kvbp   = (float*)(ws + off); off += (size_t)DEPTH*16*DIM*4;
  float* lat    = (float*)(ws + off); off += (size_t)LROWS*DIM*4;
  short* lnlat  = (short*)(ws + off); off += (size_t)LROWS*DIM*2;
  short* qkvlat = (short*)(ws + off); off += (size_t)LROWS*QKVN*2;
  short* obuf   = (short*)(ws + off); off += (size_t)LROWS*INNER*2;
  short* hbuf   = (short*)(ws + off); off += (size_t)LROWS*DIM*2;
  short* h1     = (short*)(ws + off); off += (size_t)LROWS*FFD*2;
  float* w2part = (float*)(ws + off); off += (size_t)4*LROWS*DIM*4;
  float* part_O = (float*)(ws + off); off += (size_t)1024*64*64*4;
  float* part_m = (float*)(ws + off); off += (size_t)1024*64*4;
  float* part_l = (float*)(ws + off); off += (size_t)1024*64*4;

  prep_kernel<<<XROWS/4, 256, 0, stream>>>(x, frame_e, media_e, xhat);
  latinit_kernel<<<1024, 256, 0, stream>>>(latents, lat);
  kvbp_kernel<<<dim3(16, DEPTH), 256, 0, stream>>>(lnm_b, Wkv, kvbp);
  kvbred_kernel<<<DEPTH, 256, 0, stream>>>(kvbp, kvb);

  for (int i = 0; i < DEPTH; i++) {
    tcast_all_kernel<<<2816, 256, 0, stream>>>(
        Wkv + (size_t)i*DIM*DIM, Wq + (size_t)i*DIM*INNER, Wo + (size_t)i*INNER*DIM,
        W1 + (size_t)i*DIM*FFD, W2 + (size_t)i*FFD*DIM, lnm_w + (size_t)i*DIM,
        Wkv_f, qkvW, Wo_h, W1_h, W2_h);

    ln_kernel<true><<<LROWS, 256, 0, stream>>>(lat, lnl_w + i*DIM, lnl_b + i*DIM, lnlat);
    gemm_kernel<0,false><<<dim3(LROWS/128, QKVN/128), 256, 0, stream>>>(
        lnlat, qkvW, qkvlat, nullptr, LROWS, QKVN, DIM, DIM);
    gemm256p_kernel<<<dim3(DIM/256, XROWS/256), 512, 0, stream>>>(
        xhat, Wkv_f, kvbuf, kvb + i*DIM, XROWS, DIM, DIM);
    attn_part_kernel<<<1024, 256, 0, stream>>>(qkvlat, kvbuf, part_O, part_m, part_l);
    attn_combine_kernel<<<128, 256, 0, stream>>>(part_O, part_m, part_l, obuf);
    gemm_kernel<2,false><<<dim3(LROWS/128, DIM/128), 256, 0, stream>>>(
        obuf, Wo_h, lat, nullptr, LROWS, DIM, INNER, INNER);
    ln_kernel<true><<<LROWS, 256, 0, stream>>>(lat, ffln_w + i*DIM, ffln_b + i*DIM, hbuf);
    gemm_kernel<1,true><<<dim3(LROWS/128, FFD/128), 256, 0, stream>>>(
        hbuf, W1_h, h1, b1 + (size_t)i*FFD, LROWS, FFD, DIM, DIM);
    gemm_kernel<4,false><<<dim3(LROWS/128, DIM/128, 4), 256, 0, stream>>>(
        h1, W2_h, w2part, nullptr, LROWS, DIM, DIM, FFD);
    w2red_kernel<<<1024, 256, 0, stream>>>(w2part, b2 + (size_t)i*DIM, lat);
  }
  ln_kernel<false><<<LROWS, 256, 0, stream>>>(lat, fln_w, fln_b, out);
}

// Round 6
// 2169.705 us; speedup vs baseline: 1.1869x; 1.1869x over previous
//
#include <hip/hip_runtime.h>
#include <math.h>

// PerceiverResampler on MI355X.
// xhat = rownorm(x + frame_emb + media_emb) once (bf16); per-layer LN affine folded
// into Wkv. GEMMs bf16 MFMA 16x16x32, fp32 accum, weights pre-transposed [N][K].
// Round-4 proven kv-GEMM (256x256, BK=64, 8-phase, 2 barriers/phase, vmcnt(4) gates,
// slot^(row&7) swizzle, 128KB LDS) restored verbatim; qkv-GEMM + next-layer weight
// tcast merged into the same dispatch as trailing blocks (double-buffered weights).
// LN of lat fused into latinit / w2red (each block owns one row).

#define DIM   1024
#define DEPTH 6
#define HEADS 8
#define NLAT  64
#define INNER 512
#define FFD   4096
#define XROWS 65536
#define LROWS 1024
#define NBT   16
#define QKVN  1536

typedef __attribute__((ext_vector_type(8))) short bf16x8;
typedef __attribute__((ext_vector_type(4))) float f32x4;

#define WAITV(n) asm volatile("s_waitcnt vmcnt(" #n ")" ::: "memory")

__device__ __forceinline__ short f2bf(float f) {
  union { float f; unsigned u; } v; v.f = f;
  unsigned r = v.u + 0x7fffu + ((v.u >> 16) & 1u);
  return (short)(r >> 16);
}

__device__ __forceinline__ void gload16(const void* g, void* l) {
  __builtin_amdgcn_global_load_lds(
      (const __attribute__((address_space(1))) unsigned int*)g,
      (__attribute__((address_space(3))) unsigned int*)l, 16, 0, 0);
}

__device__ __forceinline__ f32x4 zero_f4() { f32x4 z; z[0]=0.f; z[1]=0.f; z[2]=0.f; z[3]=0.f; return z; }
__device__ __forceinline__ bf16x8 zero_b8() { bf16x8 z;
#pragma unroll
  for (int e=0;e<8;e++) z[e]=0; return z; }

// ---------------- preprocess ----------------
__global__ __launch_bounds__(256)
void prep_kernel(const float* __restrict__ x, const float* __restrict__ fe,
                 const float* __restrict__ me, short* __restrict__ xhat)
{
  int lane = threadIdx.x & 63;
  int r = blockIdx.x*4 + (threadIdx.x >> 6);
  int f = (r >> 8) & 15, tt = (r >> 12) & 7;
  const float4* xp = (const float4*)(x + (size_t)r*DIM);
  const float4* fp = (const float4*)(fe + (size_t)f*DIM);
  const float4* mp = (const float4*)(me + (size_t)tt*DIM);
  float y[16];
  float s = 0.f, sq = 0.f;
#pragma unroll
  for (int k = 0; k < 4; k++) {
    float4 xv = xp[k*64 + lane], fv = fp[k*64 + lane], mv = mp[k*64 + lane];
    float a0 = xv.x+fv.x+mv.x, a1 = xv.y+fv.y+mv.y, a2 = xv.z+fv.z+mv.z, a3 = xv.w+fv.w+mv.w;
    y[k*4+0]=a0; y[k*4+1]=a1; y[k*4+2]=a2; y[k*4+3]=a3;
    s += a0+a1+a2+a3; sq += a0*a0+a1*a1+a2*a2+a3*a3;
  }
#pragma unroll
  for (int off = 32; off >= 1; off >>= 1) {
    s  += __shfl_xor(s,  off, 64);
    sq += __shfl_xor(sq, off, 64);
  }
  float mean = s * (1.0f/DIM);
  float var  = sq * (1.0f/DIM) - mean*mean;
  float rs = rsqrtf(var + 1e-5f);
  short4* op = (short4*)(xhat + (size_t)r*DIM);
#pragma unroll
  for (int k = 0; k < 4; k++) {
    short4 o;
    o.x = f2bf((y[k*4+0]-mean)*rs); o.y = f2bf((y[k*4+1]-mean)*rs);
    o.z = f2bf((y[k*4+2]-mean)*rs); o.w = f2bf((y[k*4+3]-mean)*rs);
    op[k*64 + lane] = o;
  }
}

// ---------------- block-wide 2-value reduce (256 threads) ----------------
__device__ __forceinline__ void reduce2(float& s, float& sq, float* sh) {
#pragma unroll
  for (int off = 32; off >= 1; off >>= 1) {
    s  += __shfl_xor(s,  off, 64);
    sq += __shfl_xor(sq, off, 64);
  }
  int t = threadIdx.x;
  if ((t & 63) == 0) { sh[(t >> 6)*2] = s; sh[(t >> 6)*2 + 1] = sq; }
  __syncthreads();
  s  = sh[0] + sh[2] + sh[4] + sh[6];
  sq = sh[1] + sh[3] + sh[5] + sh[7];
}

// ---------------- LN (hbuf producer) ----------------
template<bool OBF>
__global__ __launch_bounds__(256)
void ln_kernel(const float* __restrict__ in, const float* __restrict__ w,
               const float* __restrict__ b, void* __restrict__ outp)
{
  __shared__ float sh[8];
  int r = blockIdx.x, t = threadIdx.x;
  float4 xv = ((const float4*)(in + (size_t)r*DIM))[t];
  float s = xv.x+xv.y+xv.z+xv.w;
  float sq = xv.x*xv.x+xv.y*xv.y+xv.z*xv.z+xv.w*xv.w;
  reduce2(s, sq, sh);
  float mean = s*(1.0f/DIM), var = sq*(1.0f/DIM) - mean*mean;
  float rs = rsqrtf(var + 1e-5f);
  float4 wv = ((const float4*)w)[t], bv = ((const float4*)b)[t];
  float o0 = (xv.x-mean)*rs*wv.x + bv.x;
  float o1 = (xv.y-mean)*rs*wv.y + bv.y;
  float o2 = (xv.z-mean)*rs*wv.z + bv.z;
  float o3 = (xv.w-mean)*rs*wv.w + bv.w;
  if (OBF) {
    short4 o; o.x=f2bf(o0); o.y=f2bf(o1); o.z=f2bf(o2); o.w=f2bf(o3);
    ((short4*)((short*)outp + (size_t)r*DIM))[t] = o;
  } else {
    float4 o; o.x=o0; o.y=o1; o.z=o2; o.w=o3;
    ((float4*)((float*)outp + (size_t)r*DIM))[t] = o;
  }
}

// ---------------- lat init + LN(layer0 lnl) fused; one row per block ----------------
__global__ __launch_bounds__(256)
void latinit_ln_kernel(const float* __restrict__ latents, const float* __restrict__ w,
                       const float* __restrict__ b, float* __restrict__ lat,
                       short* __restrict__ lnlat)
{
  __shared__ float sh[8];
  int r = blockIdx.x, t = threadIdx.x;
  int i = r & 63;
  float4 a = ((const float4*)(latents + (size_t)i*DIM))[t];
  ((float4*)(lat + (size_t)r*DIM))[t] = a;
  float s = a.x+a.y+a.z+a.w;
  float sq = a.x*a.x+a.y*a.y+a.z*a.z+a.w*a.w;
  reduce2(s, sq, sh);
  float mean = s*(1.0f/DIM), var = sq*(1.0f/DIM) - mean*mean;
  float rs = rsqrtf(var + 1e-5f);
  float4 wv = ((const float4*)w)[t], bv = ((const float4*)b)[t];
  short4 o;
  o.x = f2bf((a.x-mean)*rs*wv.x + bv.x);
  o.y = f2bf((a.y-mean)*rs*wv.y + bv.y);
  o.z = f2bf((a.z-mean)*rs*wv.z + bv.z);
  o.w = f2bf((a.w-mean)*rs*wv.w + bv.w);
  ((short4*)(lnlat + (size_t)r*DIM))[t] = o;
}

// ---------------- kvb: split-K partials + reduce ----------------
__global__ __launch_bounds__(256)
void kvbp_kernel(const float* __restrict__ lnm_b, const float* __restrict__ Wkv,
                 float* __restrict__ kvb_part)
{
  int z = blockIdx.x, i = blockIdx.y, t = threadIdx.x;
  const float* W = Wkv + (size_t)i*DIM*DIM;
  const float* bv = lnm_b + (size_t)i*DIM;
  float acc0=0,acc1=0,acc2=0,acc3=0;
  for (int k = z*64; k < z*64+64; k++) {
    float b = bv[k];
    const float* Wr = W + (size_t)k*DIM;
    acc0 += b * Wr[t];       acc1 += b * Wr[t+256];
    acc2 += b * Wr[t+512];   acc3 += b * Wr[t+768];
  }
  float* o = kvb_part + (size_t)(i*16 + z)*DIM;
  o[t] = acc0; o[t+256] = acc1; o[t+512] = acc2; o[t+768] = acc3;
}

__global__ __launch_bounds__(256)
void kvbred_kernel(const float* __restrict__ kvb_part, float* __restrict__ kvb)
{
  int i = blockIdx.x, t = threadIdx.x;
#pragma unroll
  for (int j = 0; j < 4; j++) {
    int col = t + j*256;
    float s = 0.f;
#pragma unroll
    for (int z = 0; z < 16; z++) s += kvb_part[(size_t)(i*16 + z)*DIM + col];
    kvb[i*DIM + col] = s;
  }
}

// ---------------- tcast helpers ----------------
struct TcastArgs {
  const float* src; short* dst; const float* fold; float scale; int K, N, bx, ntx;
};

__device__ __forceinline__ TcastArgs tcast_map(
    int b, const float* Wkv, const float* Wq, const float* Wo, const float* W1,
    const float* W2, const float* lnmw, short* Wkv_f, short* qkvW,
    short* Wo_h, short* W1_h, short* W2_h)
{
  TcastArgs a; a.fold = nullptr; a.scale = 1.0f;
  if (b < 256)      { a.src=Wkv; a.dst=Wkv_f; a.fold=lnmw; a.K=1024; a.N=1024; a.bx=b;      a.ntx=16; }
  else if (b < 384) { a.src=Wq;  a.dst=qkvW;  a.scale=0.125f; a.K=1024; a.N=512; a.bx=b-256; a.ntx=8; }
  else if (b < 640) { a.src=Wkv; a.dst=qkvW+512*1024; a.K=1024; a.N=1024; a.bx=b-384; a.ntx=16; }
  else if (b < 768) { a.src=Wo;  a.dst=Wo_h;  a.K=512;  a.N=1024; a.bx=b-640; a.ntx=16; }
  else if (b < 1792){ a.src=W1;  a.dst=W1_h;  a.K=1024; a.N=4096; a.bx=b-768; a.ntx=64; }
  else              { a.src=W2;  a.dst=W2_h;  a.K=4096; a.N=1024; a.bx=b-1792; a.ntx=16; }
  return a;
}

// standalone 256-thread tcast (layer-0 bootstrap)
__global__ __launch_bounds__(256)
void tcast_all_kernel(const float* __restrict__ Wkv, const float* __restrict__ Wq,
                      const float* __restrict__ Wo, const float* __restrict__ W1,
                      const float* __restrict__ W2, const float* __restrict__ lnmw,
                      short* __restrict__ Wkv_f, short* __restrict__ qkvW,
                      short* __restrict__ Wo_h, short* __restrict__ W1_h,
                      short* __restrict__ W2_h)
{
  TcastArgs a = tcast_map(blockIdx.x, Wkv, Wq, Wo, W1, W2, lnmw, Wkv_f, qkvW, Wo_h, W1_h, W2_h);
  int n0 = (a.bx % a.ntx)*64, k0 = (a.bx / a.ntx)*64;
  __shared__ float tile[64][65];
  int t = threadIdx.x;
#pragma unroll
  for (int i = 0; i < 16; i++) {
    int rr = (t >> 6) + i*4, cc = t & 63;
    float v = a.src[(size_t)(k0+rr)*a.N + n0 + cc] * a.scale;
    if (a.fold) v *= a.fold[k0 + rr];
    tile[rr][cc] = v;
  }
  __syncthreads();
#pragma unroll
  for (int i = 0; i < 16; i++) {
    int nn = (t >> 6) + i*4, kk = t & 63;
    a.dst[(size_t)(n0+nn)*a.K + k0 + kk] = f2bf(tile[kk][nn]);
  }
}

// ---------------- mega-kernel paths (512 threads each) ----------------

// kv path: round-4 proven 256x256 8-phase GEMM. M=XROWS, N=DIM, K=DIM.
__device__ __forceinline__ void kv256_path(
    const short* __restrict__ A, const short* __restrict__ Bt,
    short* __restrict__ C, const float* __restrict__ bias, int b, char* ldsc)
{
  const int t = threadIdx.x, lane = t & 63, wid = t >> 6;
  const int wm = wid >> 2, wn = wid & 3;
  const int K = DIM, N = DIM;

  const int work = (b & 7) * 128 + (b >> 3);    // 1024 blocks, XCD-bijective
  const int bn = work & 3, bm = work >> 2;
  const int m0 = bm * 256, n0 = bn * 256;

  f32x4 acc[8][4];
#pragma unroll
  for (int m=0;m<8;m++)
#pragma unroll
    for (int n=0;n<4;n++) acc[m][n] = zero_f4();

  auto stage = [&](int tile, int mat, int half) {
    const short* src = mat ? Bt : A;
    const int base0 = (mat ? n0 : m0) + half*128;
    char* dbase = ldsc + (mat*32768 + (tile & 1)*16384 + half*8192)*2;
#pragma unroll
    for (int i = 0; i < 2; i++) {
      int chunk = i*512 + t;
      int row_h = chunk >> 3, slot = chunk & 7;
      int ss = slot ^ (row_h & 7);
      gload16(src + (size_t)(base0 + row_h)*K + tile*64 + ss*8,
              dbase + (i*512 + (wid << 6))*16);
    }
  };
  auto LDA = [&](int buf, int mf, int ks) -> bf16x8 {
    int row = wm*128 + mf*16 + (lane & 15);
    int slot = (ks*4 + (lane >> 4)) ^ (row & 7);
    return *(const bf16x8*)(ldsc + (buf*16384 + row*64)*2 + slot*16);
  };
  auto LDB = [&](int buf, int nf, int ks) -> bf16x8 {
    int row = wn*64 + nf*16 + (lane & 15);
    int slot = (ks*4 + (lane >> 4)) ^ (row & 7);
    return *(const bf16x8*)(ldsc + (32768 + buf*16384 + row*64)*2 + slot*16);
  };

#define PHASE(BUF, Q, STAGE_STMT, GATE) do {                               \
    if ((Q) == 0) {                                                        \
      _Pragma("unroll") for (int n_=0;n_<4;n_++)                           \
        _Pragma("unroll") for (int k_=0;k_<2;k_++)                         \
          bfr[n_][k_] = LDB((BUF), n_, k_);                                \
    }                                                                      \
    _Pragma("unroll") for (int i_=0;i_<2;i_++)                             \
      _Pragma("unroll") for (int k_=0;k_<2;k_++)                           \
        afr[i_][k_] = LDA((BUF), 2*(Q)+i_, k_);                            \
    STAGE_STMT;                                                            \
    GATE;                                                                  \
    __builtin_amdgcn_sched_barrier(0);                                     \
    __builtin_amdgcn_s_barrier();                                          \
    asm volatile("s_waitcnt lgkmcnt(0)" ::: "memory");                     \
    __builtin_amdgcn_sched_barrier(0);                                     \
    __builtin_amdgcn_s_setprio(1);                                         \
    _Pragma("unroll") for (int k_=0;k_<2;k_++)                             \
      _Pragma("unroll") for (int i_=0;i_<2;i_++)                           \
        _Pragma("unroll") for (int n_=0;n_<4;n_++)                         \
          acc[2*(Q)+i_][n_] = __builtin_amdgcn_mfma_f32_16x16x32_bf16(     \
              afr[i_][k_], bfr[n_][k_], acc[2*(Q)+i_][n_], 0, 0, 0);       \
    __builtin_amdgcn_s_setprio(0);                                         \
    __builtin_amdgcn_sched_barrier(0);                                     \
    __builtin_amdgcn_s_barrier();                                          \
  } while (0)

  const int NU = K >> 7;
  stage(0, 0, 0); stage(0, 0, 1); stage(0, 1, 0); stage(0, 1, 1);
  stage(1, 1, 0); stage(1, 1, 1);
  WAITV(4);
  __builtin_amdgcn_sched_barrier(0);
  __builtin_amdgcn_s_barrier();

#pragma unroll 1
  for (int u = 0; u < NU; ++u) {
    const int t0 = 2*u, t1 = t0 + 1;
    const bool more = (u + 1 < NU);
    bf16x8 bfr[4][2], afr[2][2];
    PHASE(0, 0, stage(t1, 0, 0),               (void)0);
    PHASE(0, 1, stage(t1, 0, 1),               (void)0);
    PHASE(0, 2, if (more) stage(t0+2, 1, 0),   (void)0);
    PHASE(0, 3, if (more) stage(t0+2, 1, 1),   if (more) { WAITV(4); } else { WAITV(0); });
    PHASE(1, 0, if (more) stage(t0+2, 0, 0),   (void)0);
    PHASE(1, 1, if (more) stage(t0+2, 0, 1),   (void)0);
    PHASE(1, 2, if (more) stage(t1+2, 1, 0),   (void)0);
    PHASE(1, 3, if (more) stage(t1+2, 1, 1),   if (more) { WAITV(4); });
  }
#undef PHASE

  const int g = lane >> 4;
#pragma unroll
  for (int m=0;m<8;m++) {
#pragma unroll
    for (int n=0;n<4;n++) {
#pragma unroll
      for (int r=0;r<4;r++) {
        int mm = m0 + wm*128 + m*16 + g*4 + r;
        int nn = n0 + wn*64 + n*16 + (lane & 15);
        float v = acc[m][n][r] + bias[nn];
        C[(size_t)mm*N + nn] = f2bf(v);
      }
    }
  }
}

// qkv path: 128x128 tile, 8 waves (2M x 4N, per-wave 64x32), BK=64. M=1024,N=1536,K=1024.
__device__ __forceinline__ void qkv_path(
    const short* __restrict__ A, const short* __restrict__ Bt,
    short* __restrict__ C, int q, char* ldsc)
{
  const int t = threadIdx.x, lane = t & 63, wid = t >> 6;
  const int m0 = (q & 7) * 128, n0 = (q >> 3) * 128;
  const int wr = (wid >> 2) * 64, wc = (wid & 3) * 32;
  char* As = ldsc;            // 128x64 bf16 = 16 KB
  char* Bs = ldsc + 16384;

  f32x4 acc[4][2];
#pragma unroll
  for (int i=0;i<4;i++)
#pragma unroll
    for (int j=0;j<2;j++) acc[i][j] = zero_f4();

  for (int kt = 0; kt < DIM; kt += 64) {
#pragma unroll
    for (int i = 0; i < 2; i++) {
      int chunk = i*512 + t;
      int row = chunk >> 3, slot = chunk & 7;
      int ss = slot ^ (row & 7);
      gload16(A + (size_t)(m0 + row)*DIM + kt + ss*8, As + (i*512 + (wid<<6))*16);
    }
#pragma unroll
    for (int i = 0; i < 2; i++) {
      int chunk = i*512 + t;
      int row = chunk >> 3, slot = chunk & 7;
      int ss = slot ^ (row & 7);
      gload16(Bt + (size_t)(n0 + row)*DIM + kt + ss*8, Bs + (i*512 + (wid<<6))*16);
    }
    __syncthreads();
#pragma unroll
    for (int ks = 0; ks < 2; ks++) {
      bf16x8 af[4], bfr[2];
#pragma unroll
      for (int i=0;i<4;i++) {
        int row = wr + i*16 + (lane & 15);
        int slot = (ks*4 + (lane >> 4)) ^ (row & 7);
        af[i] = *(const bf16x8*)(As + row*128 + slot*16);
      }
#pragma unroll
      for (int j=0;j<2;j++) {
        int row = wc + j*16 + (lane & 15);
        int slot = (ks*4 + (lane >> 4)) ^ (row & 7);
        bfr[j] = *(const bf16x8*)(Bs + row*128 + slot*16);
      }
#pragma unroll
      for (int i=0;i<4;i++)
#pragma unroll
        for (int j=0;j<2;j++)
          acc[i][j] = __builtin_amdgcn_mfma_f32_16x16x32_bf16(af[i], bfr[j], acc[i][j], 0, 0, 0);
    }
    __syncthreads();
  }

  const int g = lane >> 4;
#pragma unroll
  for (int i=0;i<4;i++) {
#pragma unroll
    for (int j=0;j<2;j++) {
#pragma unroll
      for (int r=0;r<4;r++) {
        int mm = m0 + wr + i*16 + g*4 + r;
        int nn = n0 + wc + j*16 + (lane & 15);
        C[(size_t)mm*QKVN + nn] = f2bf(acc[i][j][r]);
      }
    }
  }
}

// tcast path: 512 threads, one 64x64 tile per block
__device__ __forceinline__ void tcast_path(const TcastArgs& a, float* tile65)
{
  int n0 = (a.bx % a.ntx)*64, k0 = (a.bx / a.ntx)*64;
  int t = threadIdx.x;
#pragma unroll
  for (int i = 0; i < 8; i++) {
    int rr = (t >> 6) + i*8, cc = t & 63;
    float v = a.src[(size_t)(k0+rr)*a.N + n0 + cc] * a.scale;
    if (a.fold) v *= a.fold[k0 + rr];
    tile65[rr*65 + cc] = v;
  }
  __syncthreads();
#pragma unroll
  for (int i = 0; i < 8; i++) {
    int nn = (t >> 6) + i*8, kk = t & 63;
    a.dst[(size_t)(n0+nn)*a.K + k0 + kk] = f2bf(tile65[kk*65 + nn]);
  }
}

// mega: [0,1024) kv | [1024,1120) qkv | [1120,3936) tcast(next layer)
__global__ __launch_bounds__(512, 2)
void mega_kernel(const short* __restrict__ xhat, const short* __restrict__ Wkvf,
                 const float* __restrict__ kvb_i, short* __restrict__ kvbuf,
                 const short* __restrict__ lnlat, const short* __restrict__ qkvW,
                 short* __restrict__ qkvlat,
                 const float* nWkv, const float* nWq, const float* nWo,
                 const float* nW1, const float* nW2, const float* nlnmw,
                 short* dWkvf, short* dqkvW, short* dWo, short* dW1, short* dW2)
{
  __shared__ __align__(16) short lds[65536];   // 128 KiB
  int b = blockIdx.x;
  if (b < 1024) {
    kv256_path(xhat, Wkvf, kvbuf, kvb_i, b, (char*)lds);
  } else if (b < 1120) {
    qkv_path(lnlat, qkvW, qkvlat, b - 1024, (char*)lds);
  } else {
    TcastArgs a = tcast_map(b - 1120, nWkv, nWq, nWo, nW1, nW2, nlnmw,
                            dWkvf, dqkvW, dWo, dW1, dW2);
    tcast_path(a, (float*)lds);
  }
}

// ---------------- 128x128 GEMM (small shapes) ----------------
// EPI: 1 gelu+bf16, 2 f32 +=, 4 f32 partial store (split-K z)
template<int EPI, bool HAS_BIAS>
__global__ __launch_bounds__(256, 2)
void gemm_kernel(const short* __restrict__ A, const short* __restrict__ Bt,
                 void* __restrict__ Cout, const float* __restrict__ bias,
                 int M, int N, int K, int ldk)
{
  __shared__ __align__(16) short As[128*64];
  __shared__ __align__(16) short Bs[128*64];
  const int t = threadIdx.x;
  const int lane = t & 63, w = t >> 6;
  const int m0 = blockIdx.x * 128, n0 = blockIdx.y * 128;
  const int wr = (w >> 1) * 64, wc = (w & 1) * 64;
  const short* Ap = A + (size_t)blockIdx.z * K;
  const short* Btp = Bt + (size_t)blockIdx.z * K;

  f32x4 acc[4][4];
#pragma unroll
  for (int i=0;i<4;i++)
#pragma unroll
    for (int j=0;j<4;j++) acc[i][j] = zero_f4();

  for (int kt = 0; kt < K; kt += 64) {
#pragma unroll
    for (int i = 0; i < 4; i++) {
      int chunk = i*256 + t;
      int row = chunk >> 3, slot = chunk & 7;
      int ss = slot ^ (row & 7);
      gload16(Ap + (size_t)(m0 + row)*ldk + kt + ss*8,
              (char*)As + (i*256 + (w<<6))*16);
    }
#pragma unroll
    for (int i = 0; i < 4; i++) {
      int chunk = i*256 + t;
      int row = chunk >> 3, slot = chunk & 7;
      int ss = slot ^ (row & 7);
      gload16(Btp + (size_t)(n0 + row)*ldk + kt + ss*8,
              (char*)Bs + (i*256 + (w<<6))*16);
    }
    __syncthreads();

#pragma unroll
    for (int ks = 0; ks < 2; ks++) {
      bf16x8 af[4], bfr[4];
#pragma unroll
      for (int i=0;i<4;i++) {
        int row = wr + i*16 + (lane & 15);
        int slot = (ks*4 + (lane >> 4)) ^ (row & 7);
        af[i] = *(const bf16x8*)((const char*)As + row*128 + slot*16);
        int nrow = wc + i*16 + (lane & 15);
        int nslot = (ks*4 + (lane >> 4)) ^ (nrow & 7);
        bfr[i] = *(const bf16x8*)((const char*)Bs + nrow*128 + nslot*16);
      }
#pragma unroll
      for (int i=0;i<4;i++)
#pragma unroll
        for (int j=0;j<4;j++)
          acc[i][j] = __builtin_amdgcn_mfma_f32_16x16x32_bf16(af[i], bfr[j], acc[i][j], 0, 0, 0);
    }
    __syncthreads();
  }

  const int g = lane >> 4;
#pragma unroll
  for (int i=0;i<4;i++) {
#pragma unroll
    for (int j=0;j<4;j++) {
#pragma unroll
      for (int r=0;r<4;r++) {
        int m = m0 + wr + i*16 + g*4 + r;
        int n = n0 + wc + j*16 + (lane & 15);
        float v = acc[i][j][r];
        if (EPI == 1) {
          if (HAS_BIAS) v += bias[n];
          float gl = 0.5f * v * (1.0f + erff(v * 0.70710678f));
          ((short*)Cout)[(size_t)m*N + n] = f2bf(gl);
        } else if (EPI == 2) {
          if (HAS_BIAS) v += bias[n];
          float* o = (float*)Cout + (size_t)m*N + n;
          *o += v;
        } else {
          ((float*)Cout)[(size_t)blockIdx.z*M*N + (size_t)m*N + n] = v;
        }
      }
    }
  }
}

// ---------------- W2 split-K reduce + residual + LN(next lnl or final fln) ----------------
template<bool LAST>
__global__ __launch_bounds__(256)
void w2red_ln_kernel(const float* __restrict__ part, const float* __restrict__ b2,
                     float* __restrict__ lat, const float* __restrict__ w,
                     const float* __restrict__ bb, void* __restrict__ dst)
{
  __shared__ float sh[8];
  int r = blockIdx.x, t = threadIdx.x;
  int idx = r*256 + t;
  float4 a = ((float4*)lat)[idx];
  float4 b4 = ((const float4*)b2)[t];
  a.x += b4.x; a.y += b4.y; a.z += b4.z; a.w += b4.w;
#pragma unroll
  for (int z = 0; z < 4; z++) {
    float4 p = ((const float4*)(part + (size_t)z*LROWS*DIM))[idx];
    a.x += p.x; a.y += p.y; a.z += p.z; a.w += p.w;
  }
  ((float4*)lat)[idx] = a;
  float s = a.x+a.y+a.z+a.w;
  float sq = a.x*a.x+a.y*a.y+a.z*a.z+a.w*a.w;
  reduce2(s, sq, sh);
  float mean = s*(1.0f/DIM), var = sq*(1.0f/DIM) - mean*mean;
  float rs = rsqrtf(var + 1e-5f);
  float4 wv = ((const float4*)w)[t], bv = ((const float4*)bb)[t];
  float o0 = (a.x-mean)*rs*wv.x + bv.x;
  float o1 = (a.y-mean)*rs*wv.y + bv.y;
  float o2 = (a.z-mean)*rs*wv.z + bv.z;
  float o3 = (a.w-mean)*rs*wv.w + bv.w;
  if (LAST) {
    float4 o; o.x=o0; o.y=o1; o.z=o2; o.w=o3;
    ((float4*)((float*)dst + (size_t)r*DIM))[t] = o;
  } else {
    short4 o; o.x=f2bf(o0); o.y=f2bf(o1); o.z=f2bf(o2); o.w=f2bf(o3);
    ((short4*)((short*)dst + (size_t)r*DIM))[t] = o;
  }
}

// ---------------- attention pass 1: split-K flash, register softmax ----------------
__global__ __launch_bounds__(256, 2)
void attn_part_kernel(const short* __restrict__ qkvlat, const short* __restrict__ kvbuf,
                      float* __restrict__ part_O, float* __restrict__ part_m,
                      float* __restrict__ part_l)
{
  __shared__ __align__(16) short q_sh[64*64];
  __shared__ __align__(16) short K_sh[128*64];
  __shared__ __align__(16) short VT_sh[64*128];
  __shared__ __align__(16) short P_sh[64*132];

  const int t = threadIdx.x, lane = t & 63, w = t >> 6;
  const int bid = blockIdx.x;
  const int s = bid & 7, bh = bid >> 3;
  const int h = bh & 7, bt = bh >> 3;

  {
    const short* qsrc = qkvlat + (size_t)(bt*64)*QKVN + h*64;
#pragma unroll
    for (int i = 0; i < 2; i++) {
      int chunk = i*256 + t;
      int row = chunk >> 3, slot = chunk & 7;
      gload16(qsrc + (size_t)row*QKVN + ((slot ^ (row & 7))*8),
              (char*)q_sh + (i*256 + (w<<6))*16);
    }
  }

  float m_run[4], l_run[4];
#pragma unroll
  for (int r=0;r<4;r++){ m_run[r] = -1e30f; l_run[r] = 0.f; }
  f32x4 oacc[4];
#pragma unroll
  for (int j=0;j<4;j++) oacc[j] = zero_f4();

  const int nch = (s == 7) ? 5 : 4;
  for (int c5 = 0; c5 < nch; c5++) {
    __syncthreads();
    const bool isLat = (c5 == 4);
    const int jv = isLat ? 4 : 8;
    const short* kbase; int kstride, valid;
    if (!isLat) {
      kbase = kvbuf + ((size_t)bt*4096 + (s*4 + c5)*128)*DIM + h*64;
      kstride = DIM; valid = 128;
    } else {
      kbase = qkvlat + (size_t)(bt*64)*QKVN + 512 + h*64;
      kstride = QKVN; valid = 64;
    }
    const short* vbase = kbase + 512;

#pragma unroll
    for (int i = 0; i < 4; i++) {
      int chunk = i*256 + t;
      int row = chunk >> 3, slot = chunk & 7;
      gload16(kbase + (size_t)row*kstride + ((slot ^ (row & 7))*8),
              (char*)K_sh + (i*256 + (w<<6))*16);
    }
#pragma unroll
    for (int i = 0; i < 4; i++) {
      int c = i*256 + t;
      int row = c >> 3, slot = c & 7;
      bf16x8 v = (row < valid) ? *(const bf16x8*)(vbase + (size_t)row*kstride + slot*8) : zero_b8();
      int kslot = row >> 3;
#pragma unroll
      for (int e=0;e<8;e++) {
        int dh = slot*8 + e;
        VT_sh[dh*128 + ((kslot ^ (dh & 7))*8) + (row & 7)] = v[e];
      }
    }
    __syncthreads();

    f32x4 sacc[8];
#pragma unroll
    for (int j=0;j<8;j++) sacc[j] = zero_f4();
#pragma unroll
    for (int ks=0; ks<2; ks++) {
      int arow = w*16 + (lane & 15);
      int aslot = (ks*4 + (lane >> 4)) ^ (arow & 7);
      bf16x8 af = *(const bf16x8*)((const char*)q_sh + arow*128 + aslot*16);
#pragma unroll
      for (int j=0;j<8;j++) {
        int brow = j*16 + (lane & 15);
        int bslot = (ks*4 + (lane >> 4)) ^ (brow & 7);
        bf16x8 bv = *(const bf16x8*)((const char*)K_sh + brow*128 + bslot*16);
        sacc[j] = __builtin_amdgcn_mfma_f32_16x16x32_bf16(af, bv, sacc[j], 0, 0, 0);
      }
    }

    float mx[4];
#pragma unroll
    for (int r=0;r<4;r++) mx[r] = -1e30f;
#pragma unroll
    for (int j=0;j<8;j++) {
      if (j < jv) {
#pragma unroll
        for (int r=0;r<4;r++) mx[r] = fmaxf(mx[r], sacc[j][r]);
      }
    }
#pragma unroll
    for (int m2=1; m2<16; m2<<=1) {
#pragma unroll
      for (int r=0;r<4;r++) mx[r] = fmaxf(mx[r], __shfl_xor(mx[r], m2, 64));
    }
    float alpha[4], rowsum[4];
#pragma unroll
    for (int r=0;r<4;r++) {
      float nm = fmaxf(m_run[r], mx[r]);
      alpha[r] = __expf(m_run[r] - nm);
      m_run[r] = nm;
      rowsum[r] = 0.f;
    }
#pragma unroll
    for (int j=0;j<8;j++) {
#pragma unroll
      for (int r=0;r<4;r++) {
        float p = 0.f;
        if (j < jv) { p = __expf(sacc[j][r] - m_run[r]); rowsum[r] += p; }
        P_sh[(w*16 + (lane>>4)*4 + r)*132 + j*16 + (lane & 15)] = f2bf(p);
      }
    }
#pragma unroll
    for (int m2=1; m2<16; m2<<=1) {
#pragma unroll
      for (int r=0;r<4;r++) rowsum[r] += __shfl_xor(rowsum[r], m2, 64);
    }
#pragma unroll
    for (int r=0;r<4;r++) l_run[r] = l_run[r]*alpha[r] + rowsum[r];
#pragma unroll
    for (int j=0;j<4;j++) {
#pragma unroll
      for (int r=0;r<4;r++) oacc[j][r] *= alpha[r];
    }
    __syncthreads();

#pragma unroll
    for (int ks=0; ks<4; ks++) {
      int prow = w*16 + (lane & 15);
      bf16x8 af = *(const bf16x8*)((const char*)P_sh + prow*264 + ks*64 + (lane >> 4)*16);
#pragma unroll
      for (int j=0;j<4;j++) {
        int dh = j*16 + (lane & 15);
        int kslot = (ks*4 + (lane >> 4)) ^ (dh & 7);
        bf16x8 bv = *(const bf16x8*)((const char*)VT_sh + dh*256 + kslot*16);
        oacc[j] = __builtin_amdgcn_mfma_f32_16x16x32_bf16(af, bv, oacc[j], 0, 0, 0);
      }
    }
  }

  {
    float* Ob = part_O + (size_t)bid*4096;
    int rbase = w*16 + (lane>>4)*4;
#pragma unroll
    for (int j=0;j<4;j++) {
#pragma unroll
      for (int r=0;r<4;r++)
        Ob[(rbase + r)*64 + j*16 + (lane & 15)] = oacc[j][r];
    }
    if ((lane & 15) == 0) {
#pragma unroll
      for (int r=0;r<4;r++) {
        part_m[(size_t)bid*64 + rbase + r] = m_run[r];
        part_l[(size_t)bid*64 + rbase + r] = l_run[r];
      }
    }
  }
}

// ---------------- attention pass 2 ----------------
__global__ __launch_bounds__(256)
void attn_combine_kernel(const float* __restrict__ part_O, const float* __restrict__ part_m,
                         const float* __restrict__ part_l, short* __restrict__ obuf)
{
  int bh = blockIdx.x, t = threadIdx.x;
  int q = t >> 2, c0 = (t & 3) * 16;
  int bt = bh >> 3, h = bh & 7;
  float m8[8], w8[8];
  float mmax = -1e30f;
#pragma unroll
  for (int s=0;s<8;s++) { m8[s] = part_m[(size_t)(bh*8+s)*64 + q]; mmax = fmaxf(mmax, m8[s]); }
  float lt = 0.f;
#pragma unroll
  for (int s=0;s<8;s++) { w8[s] = __expf(m8[s] - mmax); lt += w8[s] * part_l[(size_t)(bh*8+s)*64 + q]; }
  float inv = 1.0f / lt;
  float4 acc[4];
#pragma unroll
  for (int u=0;u<4;u++) { acc[u].x=0.f; acc[u].y=0.f; acc[u].z=0.f; acc[u].w=0.f; }
#pragma unroll
  for (int s=0;s<8;s++) {
    const float4* Ob = (const float4*)(part_O + ((size_t)(bh*8+s)*64 + q)*64 + c0);
#pragma unroll
    for (int u=0;u<4;u++) {
      float4 v = Ob[u];
      acc[u].x += w8[s]*v.x; acc[u].y += w8[s]*v.y;
      acc[u].z += w8[s]*v.z; acc[u].w += w8[s]*v.w;
    }
  }
  short* ob = obuf + (size_t)(bt*64 + q)*INNER + h*64 + c0;
#pragma unroll
  for (int u=0;u<4;u++) {
    short4 o;
    o.x = f2bf(acc[u].x*inv); o.y = f2bf(acc[u].y*inv);
    o.z = f2bf(acc[u].z*inv); o.w = f2bf(acc[u].w*inv);
    ((short4*)ob)[u] = o;
  }
}

// ---------------- launch ----------------
extern "C" void kernel_launch(void* const* d_in, const int* in_sizes, int n_in,
                              void* d_out, int out_size, void* d_ws, size_t ws_size,
                              hipStream_t stream)
{
  (void)in_sizes; (void)n_in; (void)out_size; (void)ws_size;
  const float* x        = (const float*)d_in[0];
  const float* latents  = (const float*)d_in[1];
  const float* frame_e  = (const float*)d_in[2];
  const float* media_e  = (const float*)d_in[3];
  const float* lnm_w    = (const float*)d_in[4];
  const float* lnm_b    = (const float*)d_in[5];
  const float* lnl_w    = (const float*)d_in[6];
  const float* lnl_b    = (const float*)d_in[7];
  const float* Wq       = (const float*)d_in[8];
  const float* Wkv      = (const float*)d_in[9];
  const float* Wo       = (const float*)d_in[10];
  const float* ffln_w   = (const float*)d_in[11];
  const float* ffln_b   = (const float*)d_in[12];
  const float* W1       = (const float*)d_in[13];
  const float* b1       = (const float*)d_in[14];
  const float* W2       = (const float*)d_in[15];
  const float* b2       = (const float*)d_in[16];
  const float* fln_w    = (const float*)d_in[17];
  const float* fln_b    = (const float*)d_in[18];
  float* out = (float*)d_out;

  char* ws = (char*)d_ws;
  size_t off = 0;
  short* xhat   = (short*)(ws + off); off += (size_t)XROWS*DIM*2;
  short* kvbuf  = (short*)(ws + off); off += (size_t)XROWS*DIM*2;
  short* Wkvf_b[2]; short* qkvW_b[2]; short* Wo_b[2]; short* W1_b[2]; short* W2_b[2];
  for (int j = 0; j < 2; j++) {
    Wkvf_b[j] = (short*)(ws + off); off += (size_t)DIM*DIM*2;
    qkvW_b[j] = (short*)(ws + off); off += (size_t)QKVN*DIM*2;
    Wo_b[j]   = (short*)(ws + off); off += (size_t)INNER*DIM*2;
    W1_b[j]   = (short*)(ws + off); off += (size_t)DIM*FFD*2;
    W2_b[j]   = (short*)(ws + off); off += (size_t)FFD*DIM*2;
  }
  float* kvb    = (float*)(ws + off); off += (size_t)DEPTH*DIM*4;
  float* kvbp   = (float*)(ws + off); off += (size_t)DEPTH*16*DIM*4;
  float* lat    = (float*)(ws + off); off += (size_t)LROWS*DIM*4;
  short* lnlat  = (short*)(ws + off); off += (size_t)LROWS*DIM*2;
  short* qkvlat = (short*)(ws + off); off += (size_t)LROWS*QKVN*2;
  short* obuf   = (short*)(ws + off); off += (size_t)LROWS*INNER*2;
  short* hbuf   = (short*)(ws + off); off += (size_t)LROWS*DIM*2;
  short* h1     = (short*)(ws + off); off += (size_t)LROWS*FFD*2;
  float* w2part = (float*)(ws + off); off += (size_t)4*LROWS*DIM*4;
  float* part_O = (float*)(ws + off); off += (size_t)1024*64*64*4;
  float* part_m = (float*)(ws + off); off += (size_t)1024*64*4;
  float* part_l = (float*)(ws + off); off += (size_t)1024*64*4;

  prep_kernel<<<XROWS/4, 256, 0, stream>>>(x, frame_e, media_e, xhat);
  latinit_ln_kernel<<<LROWS, 256, 0, stream>>>(latents, lnl_w, lnl_b, lat, lnlat);
  kvbp_kernel<<<dim3(16, DEPTH), 256, 0, stream>>>(lnm_b, Wkv, kvbp);
  kvbred_kernel<<<DEPTH, 256, 0, stream>>>(kvbp, kvb);
  tcast_all_kernel<<<2816, 256, 0, stream>>>(
      Wkv, Wq, Wo, W1, W2, lnm_w, Wkvf_b[0], qkvW_b[0], Wo_b[0], W1_b[0], W2_b[0]);

  for (int i = 0; i < DEPTH; i++) {
    const int cur = i & 1, nxt = (i + 1) & 1;
    const int ni = (i + 1 < DEPTH) ? (i + 1) : 0;   // unused when i==5 (grid excludes tcast)
    mega_kernel<<<(i < DEPTH-1) ? 3936 : 1120, 512, 0, stream>>>(
        xhat, Wkvf_b[cur], kvb + i*DIM, kvbuf, lnlat, qkvW_b[cur], qkvlat,
        Wkv + (size_t)ni*DIM*DIM, Wq + (size_t)ni*DIM*INNER, Wo + (size_t)ni*INNER*DIM,
        W1 + (size_t)ni*DIM*FFD, W2 + (size_t)ni*FFD*DIM, lnm_w + (size_t)ni*DIM,
        Wkvf_b[nxt], qkvW_b[nxt], Wo_b[nxt], W1_b[nxt], W2_b[nxt]);

    attn_part_kernel<<<1024, 256, 0, stream>>>(qkvlat, kvbuf, part_O, part_m, part_l);
    attn_combine_kernel<<<128, 256, 0, stream>>>(part_O, part_m, part_l, obuf);
    gemm_kernel<2,false><<<dim3(LROWS/128, DIM/128), 256, 0, stream>>>(
        obuf, Wo_b[cur], lat, nullptr, LROWS, DIM, INNER, INNER);
    ln_kernel<true><<<LROWS, 256, 0, stream>>>(lat, ffln_w + i*DIM, ffln_b + i*DIM, hbuf);
    gemm_kernel<1,true><<<dim3(LROWS/128, FFD/128), 256, 0, stream>>>(
        hbuf, W1_b[cur], h1, b1 + (size_t)i*FFD, LROWS, FFD, DIM, DIM);
    gemm_kernel<4,false><<<dim3(LROWS/128, DIM/128, 4), 256, 0, stream>>>(
        h1, W2_b[cur], w2part, nullptr, LROWS, DIM, DIM, FFD);
    if (i < DEPTH-1)
      w2red_ln_kernel<false><<<LROWS, 256, 0, stream>>>(
          w2part, b2 + (size_t)i*DIM, lat, lnl_w + (i+1)*DIM, lnl_b + (i+1)*DIM, lnlat);
    else
      w2red_ln_kernel<true><<<LROWS, 256, 0, stream>>>(
          w2part, b2 + (size_t)i*DIM, lat, fln_w, fln_b, out);
  }
}

// Round 7
// 2076.954 us; speedup vs baseline: 1.2400x; 1.0447x over previous
//
#include <hip/hip_runtime.h>
#include <math.h>

// PerceiverResampler on MI355X.
// xhat = rownorm(x + frame_emb + media_emb) once (bf16); per-layer LN affine folded
// into Wkv. GEMMs bf16 MFMA 16x16x32, fp32 accum, weights pre-transposed [N][K].
// kv-GEMM: round-4 8-phase 256x256 pipeline with HOISTED ADDRESSING: all ds_read
// fragment addresses are 4 per-thread bases + compile-time immediate offsets
// (row&7==lane&7 collapses the swizzle); staging pointers hoisted likewise.
// Separate dispatches (round-6 fusion regressed: riders contend with kv pipeline).

#define DIM   1024
#define DEPTH 6
#define HEADS 8
#define NLAT  64
#define INNER 512
#define FFD   4096
#define XROWS 65536
#define LROWS 1024
#define NBT   16
#define QKVN  1536

typedef __attribute__((ext_vector_type(8))) short bf16x8;
typedef __attribute__((ext_vector_type(4))) float f32x4;

#define WAITV(n) asm volatile("s_waitcnt vmcnt(" #n ")" ::: "memory")

__device__ __forceinline__ short f2bf(float f) {
  union { float f; unsigned u; } v; v.f = f;
  unsigned r = v.u + 0x7fffu + ((v.u >> 16) & 1u);
  return (short)(r >> 16);
}

__device__ __forceinline__ void gload16(const void* g, void* l) {
  __builtin_amdgcn_global_load_lds(
      (const __attribute__((address_space(1))) unsigned int*)g,
      (__attribute__((address_space(3))) unsigned int*)l, 16, 0, 0);
}

__device__ __forceinline__ f32x4 zero_f4() { f32x4 z; z[0]=0.f; z[1]=0.f; z[2]=0.f; z[3]=0.f; return z; }
__device__ __forceinline__ bf16x8 zero_b8() { bf16x8 z;
#pragma unroll
  for (int e=0;e<8;e++) z[e]=0; return z; }

// ---------------- preprocess ----------------
__global__ __launch_bounds__(256)
void prep_kernel(const float* __restrict__ x, const float* __restrict__ fe,
                 const float* __restrict__ me, short* __restrict__ xhat)
{
  int lane = threadIdx.x & 63;
  int r = blockIdx.x*4 + (threadIdx.x >> 6);
  int f = (r >> 8) & 15, tt = (r >> 12) & 7;
  const float4* xp = (const float4*)(x + (size_t)r*DIM);
  const float4* fp = (const float4*)(fe + (size_t)f*DIM);
  const float4* mp = (const float4*)(me + (size_t)tt*DIM);
  float y[16];
  float s = 0.f, sq = 0.f;
#pragma unroll
  for (int k = 0; k < 4; k++) {
    float4 xv = xp[k*64 + lane], fv = fp[k*64 + lane], mv = mp[k*64 + lane];
    float a0 = xv.x+fv.x+mv.x, a1 = xv.y+fv.y+mv.y, a2 = xv.z+fv.z+mv.z, a3 = xv.w+fv.w+mv.w;
    y[k*4+0]=a0; y[k*4+1]=a1; y[k*4+2]=a2; y[k*4+3]=a3;
    s += a0+a1+a2+a3; sq += a0*a0+a1*a1+a2*a2+a3*a3;
  }
#pragma unroll
  for (int off = 32; off >= 1; off >>= 1) {
    s  += __shfl_xor(s,  off, 64);
    sq += __shfl_xor(sq, off, 64);
  }
  float mean = s * (1.0f/DIM);
  float var  = sq * (1.0f/DIM) - mean*mean;
  float rs = rsqrtf(var + 1e-5f);
  short4* op = (short4*)(xhat + (size_t)r*DIM);
#pragma unroll
  for (int k = 0; k < 4; k++) {
    short4 o;
    o.x = f2bf((y[k*4+0]-mean)*rs); o.y = f2bf((y[k*4+1]-mean)*rs);
    o.z = f2bf((y[k*4+2]-mean)*rs); o.w = f2bf((y[k*4+3]-mean)*rs);
    op[k*64 + lane] = o;
  }
}

// ---------------- block-wide 2-value reduce ----------------
__device__ __forceinline__ void reduce2(float& s, float& sq, float* sh) {
#pragma unroll
  for (int off = 32; off >= 1; off >>= 1) {
    s  += __shfl_xor(s,  off, 64);
    sq += __shfl_xor(sq, off, 64);
  }
  int t = threadIdx.x;
  if ((t & 63) == 0) { sh[(t >> 6)*2] = s; sh[(t >> 6)*2 + 1] = sq; }
  __syncthreads();
  s  = sh[0] + sh[2] + sh[4] + sh[6];
  sq = sh[1] + sh[3] + sh[5] + sh[7];
}

// ---------------- LN (hbuf producer) ----------------
template<bool OBF>
__global__ __launch_bounds__(256)
void ln_kernel(const float* __restrict__ in, const float* __restrict__ w,
               const float* __restrict__ b, void* __restrict__ outp)
{
  __shared__ float sh[8];
  int r = blockIdx.x, t = threadIdx.x;
  float4 xv = ((const float4*)(in + (size_t)r*DIM))[t];
  float s = xv.x+xv.y+xv.z+xv.w;
  float sq = xv.x*xv.x+xv.y*xv.y+xv.z*xv.z+xv.w*xv.w;
  reduce2(s, sq, sh);
  float mean = s*(1.0f/DIM), var = sq*(1.0f/DIM) - mean*mean;
  float rs = rsqrtf(var + 1e-5f);
  float4 wv = ((const float4*)w)[t], bv = ((const float4*)b)[t];
  float o0 = (xv.x-mean)*rs*wv.x + bv.x;
  float o1 = (xv.y-mean)*rs*wv.y + bv.y;
  float o2 = (xv.z-mean)*rs*wv.z + bv.z;
  float o3 = (xv.w-mean)*rs*wv.w + bv.w;
  if (OBF) {
    short4 o; o.x=f2bf(o0); o.y=f2bf(o1); o.z=f2bf(o2); o.w=f2bf(o3);
    ((short4*)((short*)outp + (size_t)r*DIM))[t] = o;
  } else {
    float4 o; o.x=o0; o.y=o1; o.z=o2; o.w=o3;
    ((float4*)((float*)outp + (size_t)r*DIM))[t] = o;
  }
}

// ---------------- lat init + LN(layer0 lnl); one row per block ----------------
__global__ __launch_bounds__(256)
void latinit_ln_kernel(const float* __restrict__ latents, const float* __restrict__ w,
                       const float* __restrict__ b, float* __restrict__ lat,
                       short* __restrict__ lnlat)
{
  __shared__ float sh[8];
  int r = blockIdx.x, t = threadIdx.x;
  int i = r & 63;
  float4 a = ((const float4*)(latents + (size_t)i*DIM))[t];
  ((float4*)(lat + (size_t)r*DIM))[t] = a;
  float s = a.x+a.y+a.z+a.w;
  float sq = a.x*a.x+a.y*a.y+a.z*a.z+a.w*a.w;
  reduce2(s, sq, sh);
  float mean = s*(1.0f/DIM), var = sq*(1.0f/DIM) - mean*mean;
  float rs = rsqrtf(var + 1e-5f);
  float4 wv = ((const float4*)w)[t], bv = ((const float4*)b)[t];
  short4 o;
  o.x = f2bf((a.x-mean)*rs*wv.x + bv.x);
  o.y = f2bf((a.y-mean)*rs*wv.y + bv.y);
  o.z = f2bf((a.z-mean)*rs*wv.z + bv.z);
  o.w = f2bf((a.w-mean)*rs*wv.w + bv.w);
  ((short4*)(lnlat + (size_t)r*DIM))[t] = o;
}

// ---------------- kvb: split-K partials + reduce ----------------
__global__ __launch_bounds__(256)
void kvbp_kernel(const float* __restrict__ lnm_b, const float* __restrict__ Wkv,
                 float* __restrict__ kvb_part)
{
  int z = blockIdx.x, i = blockIdx.y, t = threadIdx.x;
  const float* W = Wkv + (size_t)i*DIM*DIM;
  const float* bv = lnm_b + (size_t)i*DIM;
  float acc0=0,acc1=0,acc2=0,acc3=0;
  for (int k = z*64; k < z*64+64; k++) {
    float b = bv[k];
    const float* Wr = W + (size_t)k*DIM;
    acc0 += b * Wr[t];       acc1 += b * Wr[t+256];
    acc2 += b * Wr[t+512];   acc3 += b * Wr[t+768];
  }
  float* o = kvb_part + (size_t)(i*16 + z)*DIM;
  o[t] = acc0; o[t+256] = acc1; o[t+512] = acc2; o[t+768] = acc3;
}

__global__ __launch_bounds__(256)
void kvbred_kernel(const float* __restrict__ kvb_part, float* __restrict__ kvb)
{
  int i = blockIdx.x, t = threadIdx.x;
#pragma unroll
  for (int j = 0; j < 4; j++) {
    int col = t + j*256;
    float s = 0.f;
#pragma unroll
    for (int z = 0; z < 16; z++) s += kvb_part[(size_t)(i*16 + z)*DIM + col];
    kvb[i*DIM + col] = s;
  }
}

// ---------------- batched transpose-cast ----------------
__global__ __launch_bounds__(256)
void tcast_all_kernel(const float* __restrict__ Wkv, const float* __restrict__ Wq,
                      const float* __restrict__ Wo, const float* __restrict__ W1,
                      const float* __restrict__ W2, const float* __restrict__ lnmw,
                      short* __restrict__ Wkv_f, short* __restrict__ qkvW,
                      short* __restrict__ Wo_h, short* __restrict__ W1_h,
                      short* __restrict__ W2_h)
{
  int b = blockIdx.x;
  const float* src; short* dst; const float* fold = nullptr; float scale = 1.0f;
  int K, N, bx, ntx;
  if (b < 256)      { src=Wkv; dst=Wkv_f; fold=lnmw; K=1024; N=1024; bx=b;      ntx=16; }
  else if (b < 384) { src=Wq;  dst=qkvW;  scale=0.125f; K=1024; N=512; bx=b-256; ntx=8; }
  else if (b < 640) { src=Wkv; dst=qkvW+512*1024; K=1024; N=1024; bx=b-384; ntx=16; }
  else if (b < 768) { src=Wo;  dst=Wo_h;  K=512;  N=1024; bx=b-640; ntx=16; }
  else if (b < 1792){ src=W1;  dst=W1_h;  K=1024; N=4096; bx=b-768; ntx=64; }
  else              { src=W2;  dst=W2_h;  K=4096; N=1024; bx=b-1792; ntx=16; }
  int n0 = (bx % ntx)*64, k0 = (bx / ntx)*64;
  __shared__ float tile[64][65];
  int t = threadIdx.x;
#pragma unroll
  for (int i = 0; i < 16; i++) {
    int rr = (t >> 6) + i*4, cc = t & 63;
    float v = src[(size_t)(k0+rr)*N + n0 + cc] * scale;
    if (fold) v *= fold[k0 + rr];
    tile[rr][cc] = v;
  }
  __syncthreads();
#pragma unroll
  for (int i = 0; i < 16; i++) {
    int nn = (t >> 6) + i*4, kk = t & 63;
    dst[(size_t)(n0+nn)*K + k0 + kk] = f2bf(tile[kk][nn]);
  }
}

// ---------------- 256x256 8-phase pipelined GEMM, hoisted addressing ----------------
// C[M][N](bf16) = A[M][K] @ Bt[N][K] + bias. K = 1024.
// LDS: A[2][2half][128][64] | B[2][2half][128][64] = 128 KiB. 8 waves (2M x 4N).
// Per phase: {ds-read frags (base+imm offsets) | stage 1 half-tile | gate} barrier
// lgkmcnt(0) setprio MFMA x16 barrier. vmcnt(4) at p3/p7 steady, vmcnt(0) tail.
__global__ __launch_bounds__(512, 1)
void gemm256p_kernel(const short* __restrict__ A, const short* __restrict__ Bt,
                     short* __restrict__ C, const float* __restrict__ bias,
                     int M, int N, int K)
{
  __shared__ __align__(16) short lds[65536];   // 128 KiB
  char* ldsc = (char*)lds;
  const int t = threadIdx.x, lane = t & 63, wid = t >> 6;
  const int wm = wid >> 2, wn = wid & 3;

  // XCD-bijective swizzle (nwg % 8 == 0); consecutive works share bm -> A L2 reuse
  const int nwg = gridDim.x * gridDim.y;
  const int id = blockIdx.y * gridDim.x + blockIdx.x;
  const int work = (id & 7) * (nwg >> 3) + (id >> 3);
  const int bn = work % gridDim.x, bm = work / gridDim.x;
  const int m0 = bm * 256, n0 = bn * 256;

  f32x4 acc[8][4];
#pragma unroll
  for (int m=0;m<8;m++)
#pragma unroll
    for (int n=0;n<4;n++) acc[m][n] = zero_f4();

  // ---- hoisted staging addresses (per thread, loop-invariant) ----
  const int hK = K << 7;                 // 128*K elements (half-tile row stride)
  const short* pA[2]; const short* pB[2]; int ldst[2];
#pragma unroll
  for (int i = 0; i < 2; i++) {
    int chunk = i*512 + t;
    int rh = chunk >> 3, sl = chunk & 7;
    int ss = sl ^ (rh & 7);              // pre-swizzled global source
    pA[i] = A + (size_t)(m0 + rh)*K + ss*8;
    pB[i] = Bt + (size_t)(n0 + rh)*K + ss*8;
    ldst[i] = (i*512 + (wid << 6))*16;   // byte offset within (mat,buf,half) region
  }
  auto stage = [&](int tile, int mat, int half) {
    char* dbase = ldsc + mat*65536 + (tile & 1)*32768 + half*16384;
#pragma unroll
    for (int i = 0; i < 2; i++) {
      const short* src = (mat ? pB[i] : pA[i]) + half*hK + tile*64;
      gload16(src, dbase + ldst[i]);
    }
  };

  // ---- hoisted fragment bases: row&7 == lane&7, so swizzle slot is frag-invariant ----
  const int sk0 = (((lane >> 4)    ) ^ (lane & 7)) * 16;   // ks=0
  const int sk1 = ((4 + (lane >> 4)) ^ (lane & 7)) * 16;   // ks=1
  const int rowb = (lane & 15) * 128;
  const char* aB[2] = { ldsc + wm*16384 + rowb + sk0, ldsc + wm*16384 + rowb + sk1 };
  const char* bB[2] = { ldsc + 65536 + wn*8192 + rowb + sk0, ldsc + 65536 + wn*8192 + rowb + sk1 };
  // A frag (buf, mf, ks): aB[ks] + buf*32768 + mf*2048   (imm <= 47104, folds into ds offset)
  // B frag (buf, nf, ks): bB[ks] + buf*32768 + nf*2048

#define PHASE(BUF, Q, STAGE_STMT, GATE) do {                               \
    if ((Q) == 0) {                                                        \
      _Pragma("unroll") for (int n_=0;n_<4;n_++)                           \
        _Pragma("unroll") for (int k_=0;k_<2;k_++)                         \
          bfr[n_][k_] = *(const bf16x8*)(bB[k_] + (BUF)*32768 + n_*2048);  \
    }                                                                      \
    _Pragma("unroll") for (int i_=0;i_<2;i_++)                             \
      _Pragma("unroll") for (int k_=0;k_<2;k_++)                           \
        afr[i_][k_] = *(const bf16x8*)(aB[k_] + (BUF)*32768 + (2*(Q)+i_)*2048); \
    STAGE_STMT;                                                            \
    GATE;                                                                  \
    __builtin_amdgcn_sched_barrier(0);                                     \
    __builtin_amdgcn_s_barrier();                                          \
    asm volatile("s_waitcnt lgkmcnt(0)" ::: "memory");                     \
    __builtin_amdgcn_sched_barrier(0);                                     \
    __builtin_amdgcn_s_setprio(1);                                         \
    _Pragma("unroll") for (int k_=0;k_<2;k_++)                             \
      _Pragma("unroll") for (int i_=0;i_<2;i_++)                           \
        _Pragma("unroll") for (int n_=0;n_<4;n_++)                         \
          acc[2*(Q)+i_][n_] = __builtin_amdgcn_mfma_f32_16x16x32_bf16(     \
              afr[i_][k_], bfr[n_][k_], acc[2*(Q)+i_][n_], 0, 0, 0);       \
    __builtin_amdgcn_s_setprio(0);                                         \
    __builtin_amdgcn_sched_barrier(0);                                     \
    __builtin_amdgcn_s_barrier();                                          \
  } while (0)

  const int NU = K >> 7;   // iterations of 2 K-tiles
  // prologue: tile0 complete + B(1); leaves B(1)'s 4 loads in flight.
  stage(0, 0, 0); stage(0, 0, 1); stage(0, 1, 0); stage(0, 1, 1);
  stage(1, 1, 0); stage(1, 1, 1);
  WAITV(4);
  __builtin_amdgcn_sched_barrier(0);
  __builtin_amdgcn_s_barrier();

#pragma unroll 1
  for (int u = 0; u < NU; ++u) {
    const int t0 = 2*u, t1 = t0 + 1;
    const bool more = (u + 1 < NU);
    bf16x8 bfr[4][2], afr[2][2];
    PHASE(0, 0, stage(t1, 0, 0),               (void)0);
    PHASE(0, 1, stage(t1, 0, 1),               (void)0);
    PHASE(0, 2, if (more) stage(t0+2, 1, 0),   (void)0);
    PHASE(0, 3, if (more) stage(t0+2, 1, 1),   if (more) { WAITV(4); } else { WAITV(0); });
    PHASE(1, 0, if (more) stage(t0+2, 0, 0),   (void)0);
    PHASE(1, 1, if (more) stage(t0+2, 0, 1),   (void)0);
    PHASE(1, 2, if (more) stage(t1+2, 1, 0),   (void)0);
    PHASE(1, 3, if (more) stage(t1+2, 1, 1),   if (more) { WAITV(4); });
  }
#undef PHASE

  const int g = lane >> 4;
#pragma unroll
  for (int m=0;m<8;m++) {
#pragma unroll
    for (int n=0;n<4;n++) {
#pragma unroll
      for (int r=0;r<4;r++) {
        int mm = m0 + wm*128 + m*16 + g*4 + r;
        int nn = n0 + wn*64 + n*16 + (lane & 15);
        float v = acc[m][n][r] + bias[nn];
        C[(size_t)mm*N + nn] = f2bf(v);
      }
    }
  }
}

// ---------------- 128x128 GEMM (small shapes) ----------------
// EPI: 0 bf16 store, 1 gelu+bf16, 2 f32 +=, 4 f32 partial store (split-K z)
template<int EPI, bool HAS_BIAS>
__global__ __launch_bounds__(256, 2)
void gemm_kernel(const short* __restrict__ A, const short* __restrict__ Bt,
                 void* __restrict__ Cout, const float* __restrict__ bias,
                 int M, int N, int K, int ldk)
{
  __shared__ __align__(16) short As[128*64];
  __shared__ __align__(16) short Bs[128*64];
  const int t = threadIdx.x;
  const int lane = t & 63, w = t >> 6;
  const int m0 = blockIdx.x * 128, n0 = blockIdx.y * 128;
  const int wr = (w >> 1) * 64, wc = (w & 1) * 64;
  const short* Ap = A + (size_t)blockIdx.z * K;
  const short* Btp = Bt + (size_t)blockIdx.z * K;

  f32x4 acc[4][4];
#pragma unroll
  for (int i=0;i<4;i++)
#pragma unroll
    for (int j=0;j<4;j++) acc[i][j] = zero_f4();

  for (int kt = 0; kt < K; kt += 64) {
#pragma unroll
    for (int i = 0; i < 4; i++) {
      int chunk = i*256 + t;
      int row = chunk >> 3, slot = chunk & 7;
      int ss = slot ^ (row & 7);
      gload16(Ap + (size_t)(m0 + row)*ldk + kt + ss*8,
              (char*)As + (i*256 + (w<<6))*16);
    }
#pragma unroll
    for (int i = 0; i < 4; i++) {
      int chunk = i*256 + t;
      int row = chunk >> 3, slot = chunk & 7;
      int ss = slot ^ (row & 7);
      gload16(Btp + (size_t)(n0 + row)*ldk + kt + ss*8,
              (char*)Bs + (i*256 + (w<<6))*16);
    }
    __syncthreads();

#pragma unroll
    for (int ks = 0; ks < 2; ks++) {
      bf16x8 af[4], bfr[4];
#pragma unroll
      for (int i=0;i<4;i++) {
        int row = wr + i*16 + (lane & 15);
        int slot = (ks*4 + (lane >> 4)) ^ (row & 7);
        af[i] = *(const bf16x8*)((const char*)As + row*128 + slot*16);
        int nrow = wc + i*16 + (lane & 15);
        int nslot = (ks*4 + (lane >> 4)) ^ (nrow & 7);
        bfr[i] = *(const bf16x8*)((const char*)Bs + nrow*128 + nslot*16);
      }
#pragma unroll
      for (int i=0;i<4;i++)
#pragma unroll
        for (int j=0;j<4;j++)
          acc[i][j] = __builtin_amdgcn_mfma_f32_16x16x32_bf16(af[i], bfr[j], acc[i][j], 0, 0, 0);
    }
    __syncthreads();
  }

  const int g = lane >> 4;
#pragma unroll
  for (int i=0;i<4;i++) {
#pragma unroll
    for (int j=0;j<4;j++) {
#pragma unroll
      for (int r=0;r<4;r++) {
        int m = m0 + wr + i*16 + g*4 + r;
        int n = n0 + wc + j*16 + (lane & 15);
        float v = acc[i][j][r];
        if (EPI == 0) {
          if (HAS_BIAS) v += bias[n];
          ((short*)Cout)[(size_t)m*N + n] = f2bf(v);
        } else if (EPI == 1) {
          if (HAS_BIAS) v += bias[n];
          float gl = 0.5f * v * (1.0f + erff(v * 0.70710678f));
          ((short*)Cout)[(size_t)m*N + n] = f2bf(gl);
        } else if (EPI == 2) {
          if (HAS_BIAS) v += bias[n];
          float* o = (float*)Cout + (size_t)m*N + n;
          *o += v;
        } else {
          ((float*)Cout)[(size_t)blockIdx.z*M*N + (size_t)m*N + n] = v;
        }
      }
    }
  }
}

// ---------------- W2 split-K reduce + residual + LN(next lnl or final fln) ----------------
template<bool LAST>
__global__ __launch_bounds__(256)
void w2red_ln_kernel(const float* __restrict__ part, const float* __restrict__ b2,
                     float* __restrict__ lat, const float* __restrict__ w,
                     const float* __restrict__ bb, void* __restrict__ dst)
{
  __shared__ float sh[8];
  int r = blockIdx.x, t = threadIdx.x;
  int idx = r*256 + t;
  float4 a = ((float4*)lat)[idx];
  float4 b4 = ((const float4*)b2)[t];
  a.x += b4.x; a.y += b4.y; a.z += b4.z; a.w += b4.w;
#pragma unroll
  for (int z = 0; z < 4; z++) {
    float4 p = ((const float4*)(part + (size_t)z*LROWS*DIM))[idx];
    a.x += p.x; a.y += p.y; a.z += p.z; a.w += p.w;
  }
  ((float4*)lat)[idx] = a;
  float s = a.x+a.y+a.z+a.w;
  float sq = a.x*a.x+a.y*a.y+a.z*a.z+a.w*a.w;
  reduce2(s, sq, sh);
  float mean = s*(1.0f/DIM), var = sq*(1.0f/DIM) - mean*mean;
  float rs = rsqrtf(var + 1e-5f);
  float4 wv = ((const float4*)w)[t], bv = ((const float4*)bb)[t];
  float o0 = (a.x-mean)*rs*wv.x + bv.x;
  float o1 = (a.y-mean)*rs*wv.y + bv.y;
  float o2 = (a.z-mean)*rs*wv.z + bv.z;
  float o3 = (a.w-mean)*rs*wv.w + bv.w;
  if (LAST) {
    float4 o; o.x=o0; o.y=o1; o.z=o2; o.w=o3;
    ((float4*)((float*)dst + (size_t)r*DIM))[t] = o;
  } else {
    short4 o; o.x=f2bf(o0); o.y=f2bf(o1); o.z=f2bf(o2); o.w=f2bf(o3);
    ((short4*)((short*)dst + (size_t)r*DIM))[t] = o;
  }
}

// ---------------- attention pass 1: split-K flash, register softmax ----------------
__global__ __launch_bounds__(256, 2)
void attn_part_kernel(const short* __restrict__ qkvlat, const short* __restrict__ kvbuf,
                      float* __restrict__ part_O, float* __restrict__ part_m,
                      float* __restrict__ part_l)
{
  __shared__ __align__(16) short q_sh[64*64];
  __shared__ __align__(16) short K_sh[128*64];
  __shared__ __align__(16) short VT_sh[64*128];
  __shared__ __align__(16) short P_sh[64*132];

  const int t = threadIdx.x, lane = t & 63, w = t >> 6;
  const int bid = blockIdx.x;
  const int s = bid & 7, bh = bid >> 3;
  const int h = bh & 7, bt = bh >> 3;

  {
    const short* qsrc = qkvlat + (size_t)(bt*64)*QKVN + h*64;
#pragma unroll
    for (int i = 0; i < 2; i++) {
      int chunk = i*256 + t;
      int row = chunk >> 3, slot = chunk & 7;
      gload16(qsrc + (size_t)row*QKVN + ((slot ^ (row & 7))*8),
              (char*)q_sh + (i*256 + (w<<6))*16);
    }
  }

  float m_run[4], l_run[4];
#pragma unroll
  for (int r=0;r<4;r++){ m_run[r] = -1e30f; l_run[r] = 0.f; }
  f32x4 oacc[4];
#pragma unroll
  for (int j=0;j<4;j++) oacc[j] = zero_f4();

  const int nch = (s == 7) ? 5 : 4;
  for (int c5 = 0; c5 < nch; c5++) {
    __syncthreads();
    const bool isLat = (c5 == 4);
    const int jv = isLat ? 4 : 8;
    const short* kbase; int kstride, valid;
    if (!isLat) {
      kbase = kvbuf + ((size_t)bt*4096 + (s*4 + c5)*128)*DIM + h*64;
      kstride = DIM; valid = 128;
    } else {
      kbase = qkvlat + (size_t)(bt*64)*QKVN + 512 + h*64;
      kstride = QKVN; valid = 64;
    }
    const short* vbase = kbase + 512;

#pragma unroll
    for (int i = 0; i < 4; i++) {
      int chunk = i*256 + t;
      int row = chunk >> 3, slot = chunk & 7;
      gload16(kbase + (size_t)row*kstride + ((slot ^ (row & 7))*8),
              (char*)K_sh + (i*256 + (w<<6))*16);
    }
#pragma unroll
    for (int i = 0; i < 4; i++) {
      int c = i*256 + t;
      int row = c >> 3, slot = c & 7;
      bf16x8 v = (row < valid) ? *(const bf16x8*)(vbase + (size_t)row*kstride + slot*8) : zero_b8();
      int kslot = row >> 3;
#pragma unroll
      for (int e=0;e<8;e++) {
        int dh = slot*8 + e;
        VT_sh[dh*128 + ((kslot ^ (dh & 7))*8) + (row & 7)] = v[e];
      }
    }
    __syncthreads();

    f32x4 sacc[8];
#pragma unroll
    for (int j=0;j<8;j++) sacc[j] = zero_f4();
#pragma unroll
    for (int ks=0; ks<2; ks++) {
      int arow = w*16 + (lane & 15);
      int aslot = (ks*4 + (lane >> 4)) ^ (arow & 7);
      bf16x8 af = *(const bf16x8*)((const char*)q_sh + arow*128 + aslot*16);
#pragma unroll
      for (int j=0;j<8;j++) {
        int brow = j*16 + (lane & 15);
        int bslot = (ks*4 + (lane >> 4)) ^ (brow & 7);
        bf16x8 bv = *(const bf16x8*)((const char*)K_sh + brow*128 + bslot*16);
        sacc[j] = __builtin_amdgcn_mfma_f32_16x16x32_bf16(af, bv, sacc[j], 0, 0, 0);
      }
    }

    float mx[4];
#pragma unroll
    for (int r=0;r<4;r++) mx[r] = -1e30f;
#pragma unroll
    for (int j=0;j<8;j++) {
      if (j < jv) {
#pragma unroll
        for (int r=0;r<4;r++) mx[r] = fmaxf(mx[r], sacc[j][r]);
      }
    }
#pragma unroll
    for (int m2=1; m2<16; m2<<=1) {
#pragma unroll
      for (int r=0;r<4;r++) mx[r] = fmaxf(mx[r], __shfl_xor(mx[r], m2, 64));
    }
    float alpha[4], rowsum[4];
#pragma unroll
    for (int r=0;r<4;r++) {
      float nm = fmaxf(m_run[r], mx[r]);
      alpha[r] = __expf(m_run[r] - nm);
      m_run[r] = nm;
      rowsum[r] = 0.f;
    }
#pragma unroll
    for (int j=0;j<8;j++) {
#pragma unroll
      for (int r=0;r<4;r++) {
        float p = 0.f;
        if (j < jv) { p = __expf(sacc[j][r] - m_run[r]); rowsum[r] += p; }
        P_sh[(w*16 + (lane>>4)*4 + r)*132 + j*16 + (lane & 15)] = f2bf(p);
      }
    }
#pragma unroll
    for (int m2=1; m2<16; m2<<=1) {
#pragma unroll
      for (int r=0;r<4;r++) rowsum[r] += __shfl_xor(rowsum[r], m2, 64);
    }
#pragma unroll
    for (int r=0;r<4;r++) l_run[r] = l_run[r]*alpha[r] + rowsum[r];
#pragma unroll
    for (int j=0;j<4;j++) {
#pragma unroll
      for (int r=0;r<4;r++) oacc[j][r] *= alpha[r];
    }
    __syncthreads();

#pragma unroll
    for (int ks=0; ks<4; ks++) {
      int prow = w*16 + (lane & 15);
      bf16x8 af = *(const bf16x8*)((const char*)P_sh + prow*264 + ks*64 + (lane >> 4)*16);
#pragma unroll
      for (int j=0;j<4;j++) {
        int dh = j*16 + (lane & 15);
        int kslot = (ks*4 + (lane >> 4)) ^ (dh & 7);
        bf16x8 bv = *(const bf16x8*)((const char*)VT_sh + dh*256 + kslot*16);
        oacc[j] = __builtin_amdgcn_mfma_f32_16x16x32_bf16(af, bv, oacc[j], 0, 0, 0);
      }
    }
  }

  {
    float* Ob = part_O + (size_t)bid*4096;
    int rbase = w*16 + (lane>>4)*4;
#pragma unroll
    for (int j=0;j<4;j++) {
#pragma unroll
      for (int r=0;r<4;r++)
        Ob[(rbase + r)*64 + j*16 + (lane & 15)] = oacc[j][r];
    }
    if ((lane & 15) == 0) {
#pragma unroll
      for (int r=0;r<4;r++) {
        part_m[(size_t)bid*64 + rbase + r] = m_run[r];
        part_l[(size_t)bid*64 + rbase + r] = l_run[r];
      }
    }
  }
}

// ---------------- attention pass 2 ----------------
__global__ __launch_bounds__(256)
void attn_combine_kernel(const float* __restrict__ part_O, const float* __restrict__ part_m,
                         const float* __restrict__ part_l, short* __restrict__ obuf)
{
  int bh = blockIdx.x, t = threadIdx.x;
  int q = t >> 2, c0 = (t & 3) * 16;
  int bt = bh >> 3, h = bh & 7;
  float m8[8], w8[8];
  float mmax = -1e30f;
#pragma unroll
  for (int s=0;s<8;s++) { m8[s] = part_m[(size_t)(bh*8+s)*64 + q]; mmax = fmaxf(mmax, m8[s]); }
  float lt = 0.f;
#pragma unroll
  for (int s=0;s<8;s++) { w8[s] = __expf(m8[s] - mmax); lt += w8[s] * part_l[(size_t)(bh*8+s)*64 + q]; }
  float inv = 1.0f / lt;
  float4 acc[4];
#pragma unroll
  for (int u=0;u<4;u++) { acc[u].x=0.f; acc[u].y=0.f; acc[u].z=0.f; acc[u].w=0.f; }
#pragma unroll
  for (int s=0;s<8;s++) {
    const float4* Ob = (const float4*)(part_O + ((size_t)(bh*8+s)*64 + q)*64 + c0);
#pragma unroll
    for (int u=0;u<4;u++) {
      float4 v = Ob[u];
      acc[u].x += w8[s]*v.x; acc[u].y += w8[s]*v.y;
      acc[u].z += w8[s]*v.z; acc[u].w += w8[s]*v.w;
    }
  }
  short* ob = obuf + (size_t)(bt*64 + q)*INNER + h*64 + c0;
#pragma unroll
  for (int u=0;u<4;u++) {
    short4 o;
    o.x = f2bf(acc[u].x*inv); o.y = f2bf(acc[u].y*inv);
    o.z = f2bf(acc[u].z*inv); o.w = f2bf(acc[u].w*inv);
    ((short4*)ob)[u] = o;
  }
}

// ---------------- launch ----------------
extern "C" void kernel_launch(void* const* d_in, const int* in_sizes, int n_in,
                              void* d_out, int out_size, void* d_ws, size_t ws_size,
                              hipStream_t stream)
{
  (void)in_sizes; (void)n_in; (void)out_size; (void)ws_size;
  const float* x        = (const float*)d_in[0];
  const float* latents  = (const float*)d_in[1];
  const float* frame_e  = (const float*)d_in[2];
  const float* media_e  = (const float*)d_in[3];
  const float* lnm_w    = (const float*)d_in[4];
  const float* lnm_b    = (const float*)d_in[5];
  const float* lnl_w    = (const float*)d_in[6];
  const float* lnl_b    = (const float*)d_in[7];
  const float* Wq       = (const float*)d_in[8];
  const float* Wkv      = (const float*)d_in[9];
  const float* Wo       = (const float*)d_in[10];
  const float* ffln_w   = (const float*)d_in[11];
  const float* ffln_b   = (const float*)d_in[12];
  const float* W1       = (const float*)d_in[13];
  const float* b1       = (const float*)d_in[14];
  const float* W2       = (const float*)d_in[15];
  const float* b2       = (const float*)d_in[16];
  const float* fln_w    = (const float*)d_in[17];
  const float* fln_b    = (const float*)d_in[18];
  float* out = (float*)d_out;

  char* ws = (char*)d_ws;
  size_t off = 0;
  short* xhat   = (short*)(ws + off); off += (size_t)XROWS*DIM*2;
  short* kvbuf  = (short*)(ws + off); off += (size_t)XROWS*DIM*2;
  short* Wkv_f  = (short*)(ws + off); off += (size_t)DIM*DIM*2;
  short* qkvW   = (short*)(ws + off); off += (size_t)QKVN*DIM*2;
  short* Wo_h   = (short*)(ws + off); off += (size_t)INNER*DIM*2;
  short* W1_h   = (short*)(ws + off); off += (size_t)DIM*FFD*2;
  short* W2_h   = (short*)(ws + off); off += (size_t)FFD*DIM*2;
  float* kvb    = (float*)(ws + off); off += (size_t)DEPTH*DIM*4;
  float* kvbp   = (float*)(ws + off); off += (size_t)DEPTH*16*DIM*4;
  float* lat    = (float*)(ws + off); off += (size_t)LROWS*DIM*4;
  short* lnlat  = (short*)(ws + off); off += (size_t)LROWS*DIM*2;
  short* qkvlat = (short*)(ws + off); off += (size_t)LROWS*QKVN*2;
  short* obuf   = (short*)(ws + off); off += (size_t)LROWS*INNER*2;
  short* hbuf   = (short*)(ws + off); off += (size_t)LROWS*DIM*2;
  short* h1     = (short*)(ws + off); off += (size_t)LROWS*FFD*2;
  float* w2part = (float*)(ws + off); off += (size_t)4*LROWS*DIM*4;
  float* part_O = (float*)(ws + off); off += (size_t)1024*64*64*4;
  float* part_m = (float*)(ws + off); off += (size_t)1024*64*4;
  float* part_l = (float*)(ws + off); off += (size_t)1024*64*4;

  prep_kernel<<<XROWS/4, 256, 0, stream>>>(x, frame_e, media_e, xhat);
  latinit_ln_kernel<<<LROWS, 256, 0, stream>>>(latents, lnl_w, lnl_b, lat, lnlat);
  kvbp_kernel<<<dim3(16, DEPTH), 256, 0, stream>>>(lnm_b, Wkv, kvbp);
  kvbred_kernel<<<DEPTH, 256, 0, stream>>>(kvbp, kvb);

  for (int i = 0; i < DEPTH; i++) {
    tcast_all_kernel<<<2816, 256, 0, stream>>>(
        Wkv + (size_t)i*DIM*DIM, Wq + (size_t)i*DIM*INNER, Wo + (size_t)i*INNER*DIM,
        W1 + (size_t)i*DIM*FFD, W2 + (size_t)i*FFD*DIM, lnm_w + (size_t)i*DIM,
        Wkv_f, qkvW, Wo_h, W1_h, W2_h);

    gemm_kernel<0,false><<<dim3(LROWS/128, QKVN/128), 256, 0, stream>>>(
        lnlat, qkvW, qkvlat, nullptr, LROWS, QKVN, DIM, DIM);
    gemm256p_kernel<<<dim3(DIM/256, XROWS/256), 512, 0, stream>>>(
        xhat, Wkv_f, kvbuf, kvb + i*DIM, XROWS, DIM, DIM);
    attn_part_kernel<<<1024, 256, 0, stream>>>(qkvlat, kvbuf, part_O, part_m, part_l);
    attn_combine_kernel<<<128, 256, 0, stream>>>(part_O, part_m, part_l, obuf);
    gemm_kernel<2,false><<<dim3(LROWS/128, DIM/128), 256, 0, stream>>>(
        obuf, Wo_h, lat, nullptr, LROWS, DIM, INNER, INNER);
    ln_kernel<true><<<LROWS, 256, 0, stream>>>(lat, ffln_w + i*DIM, ffln_b + i*DIM, hbuf);
    gemm_kernel<1,true><<<dim3(LROWS/128, FFD/128), 256, 0, stream>>>(
        hbuf, W1_h, h1, b1 + (size_t)i*FFD, LROWS, FFD, DIM, DIM);
    gemm_kernel<4,false><<<dim3(LROWS/128, DIM/128, 4), 256, 0, stream>>>(
        h1, W2_h, w2part, nullptr, LROWS, DIM, DIM, FFD);
    if (i < DEPTH-1)
      w2red_ln_kernel<false><<<LROWS, 256, 0, stream>>>(
          w2part, b2 + (size_t)i*DIM, lat, lnl_w + (i+1)*DIM, lnl_b + (i+1)*DIM, lnlat);
    else
      w2red_ln_kernel<true><<<LROWS, 256, 0, stream>>>(
          w2part, b2 + (size_t)i*DIM, lat, fln_w, fln_b, out);
  }
}